// Round 1
// baseline (707.999 us; speedup 1.0000x reference)
//
#include <hip/hip_runtime.h>
#include <stdint.h>

#define B_   8
#define S_   8192
#define H_   1024
#define HQ_  256
#define CAP_ 4096
#define M_   (B_*CAP_)   // 32768

using f32x4 = __attribute__((ext_vector_type(4))) float;
using s16x8 = __attribute__((ext_vector_type(8))) short;

__device__ __forceinline__ unsigned short f2bf(float f) {
  unsigned u = __float_as_uint(f);
  u += 0x7FFF + ((u >> 16) & 1);   // RNE
  return (unsigned short)(u >> 16);
}

__device__ __forceinline__ float gelu_t(float v) {
  float z = 0.7978845608028654f * (v + 0.044715f * v * v * v);
  return 0.5f * v * (1.0f + tanhf(z));
}

__device__ __forceinline__ void gload_lds16(const void* g, void* l) {
  __builtin_amdgcn_global_load_lds(
      (const __attribute__((address_space(1))) void*)(uintptr_t)g,
      (__attribute__((address_space(3))) void*)(uintptr_t)l,
      16, 0, 0);
}

// ---------------- Router: scores = relu(x@W1+b1)@W2+b2 ; rw = sigmoid ----------------
// fp32 register-tiled GEMM, 64 tokens x 256 hidden per block, K-step 32.
__global__ __launch_bounds__(256) void router_kernel(
    const float* __restrict__ x, const float* __restrict__ W1,
    const float* __restrict__ b1, const float* __restrict__ W2,
    const float* __restrict__ b2, float* __restrict__ scores,
    float* __restrict__ rw) {
  __shared__ float xs[64][33];          // pad 33: banks spread for stride-8 row reads
  __shared__ float wt[32][256];
  __shared__ float part[4][8][8];
  const int t = threadIdx.x;
  const int m0 = blockIdx.x * 64;
  const int tg = t & 7, cg = t >> 3;    // token group (8 tokens), col group (8 cols)

  float acc[8][8];
  #pragma unroll
  for (int i = 0; i < 8; ++i)
    #pragma unroll
    for (int j = 0; j < 8; ++j) acc[i][j] = 0.f;

  for (int k0 = 0; k0 < H_; k0 += 32) {
    #pragma unroll
    for (int u = 0; u < 2; ++u) {
      int idx = t + u * 256;
      int tok = idx >> 3, q = idx & 7;
      float4 v = *(const float4*)&x[(size_t)(m0 + tok) * H_ + k0 + q * 4];
      xs[tok][q*4+0] = v.x; xs[tok][q*4+1] = v.y;
      xs[tok][q*4+2] = v.z; xs[tok][q*4+3] = v.w;
    }
    #pragma unroll
    for (int u = 0; u < 8; ++u) {
      int idx = t + u * 256;
      int r = idx >> 6, c4 = idx & 63;
      *(float4*)&wt[r][c4*4] = *(const float4*)&W1[(size_t)(k0 + r) * HQ_ + c4 * 4];
    }
    __syncthreads();
    #pragma unroll 4
    for (int k = 0; k < 32; ++k) {
      float a[8], bv[8];
      #pragma unroll
      for (int j = 0; j < 8; ++j) bv[j] = wt[k][cg * 8 + j];
      #pragma unroll
      for (int i = 0; i < 8; ++i) a[i] = xs[tg * 8 + i][k];
      #pragma unroll
      for (int i = 0; i < 8; ++i)
        #pragma unroll
        for (int j = 0; j < 8; ++j) acc[i][j] = fmaf(a[i], bv[j], acc[i][j]);
    }
    __syncthreads();
  }

  // epilogue: relu(+b1), dot with W2, reduce over 256 hidden
  float w2v[8], b1v[8];
  #pragma unroll
  for (int j = 0; j < 8; ++j) { w2v[j] = W2[cg*8+j]; b1v[j] = b1[cg*8+j]; }
  const int lane = t & 63, wv = t >> 6;
  #pragma unroll
  for (int i = 0; i < 8; ++i) {
    float p = 0.f;
    #pragma unroll
    for (int j = 0; j < 8; ++j) {
      float h = acc[i][j] + b1v[j];
      h = fmaxf(h, 0.f);
      p = fmaf(h, w2v[j], p);
    }
    p += __shfl_xor(p, 8);
    p += __shfl_xor(p, 16);
    p += __shfl_xor(p, 32);
    if ((lane >> 3) == 0) part[wv][lane][i] = p;   // lane<8 -> lane==tg
  }
  __syncthreads();
  if (t < 64) {
    int tgi = t >> 3, ii = t & 7;
    float sc = part[0][tgi][ii] + part[1][tgi][ii] + part[2][tgi][ii] + part[3][tgi][ii] + b2[0];
    scores[m0 + t] = sc;
    rw[m0 + t] = 1.f / (1.f + expf(-sc));
  }
}

// ---------------- Top-k selection: per-row threshold + stable compaction ----------------
__global__ __launch_bounds__(1024) void topk_kernel(
    const float* __restrict__ scores, int* __restrict__ comp) {
  __shared__ float sv[S_];
  __shared__ int warp_cnt[16];
  const int b = blockIdx.x;
  const int tid = threadIdx.x;
  const float* srow = scores + (size_t)b * S_;
  for (int i = tid; i < S_; i += 1024) sv[i] = srow[i];
  __syncthreads();

  // bitonic sort ascending
  for (int k = 2; k <= S_; k <<= 1) {
    for (int j = k >> 1; j > 0; j >>= 1) {
      for (int tt = tid; tt < S_/2; tt += 1024) {
        int i = ((tt & ~(j - 1)) << 1) | (tt & (j - 1));
        int ixj = i + j;
        bool up = ((i & k) == 0);
        float a = sv[i], c = sv[ixj];
        if ((a > c) == up) { sv[i] = c; sv[ixj] = a; }
      }
      __syncthreads();
    }
  }
  const float T = sv[S_ - CAP_];   // 4096-th largest
  int* crow = comp + b * CAP_;
  const int lane = tid & 63, wid = tid >> 6;

  // pass 1: strictly greater, index order
  int base = 0;
  for (int chunk = 0; chunk < S_/1024; ++chunk) {
    int idx = chunk * 1024 + tid;
    float s = srow[idx];
    bool f = s > T;
    unsigned long long m = __ballot(f);
    if (lane == 0) warp_cnt[wid] = __popcll(m);
    __syncthreads();
    int off = base; for (int w2 = 0; w2 < wid; ++w2) off += warp_cnt[w2];
    int tot = 0;    for (int w2 = 0; w2 < 16;  ++w2) tot += warp_cnt[w2];
    if (f) crow[off + __popcll(m & ((1ull << lane) - 1))] = idx;
    base += tot;
    __syncthreads();
  }
  const int cnt_gt = base;
  const int need = CAP_ - cnt_gt;
  // pass 2: equal to T, lowest indices first (jax tie rule)
  int base2 = 0;
  for (int chunk = 0; chunk < S_/1024 && base2 < need; ++chunk) {
    int idx = chunk * 1024 + tid;
    float s = srow[idx];
    bool f = (s == T);
    unsigned long long m = __ballot(f);
    if (lane == 0) warp_cnt[wid] = __popcll(m);
    __syncthreads();
    int off = base2; for (int w2 = 0; w2 < wid; ++w2) off += warp_cnt[w2];
    int tot = 0;     for (int w2 = 0; w2 < 16;  ++w2) tot += warp_cnt[w2];
    int pos = off + __popcll(m & ((1ull << lane) - 1));
    if (f && pos < need) crow[cnt_gt + pos] = idx;
    base2 += tot;
    __syncthreads();
  }
}

// ---------------- Wl -> WlT (bf16, transposed) ----------------
__global__ __launch_bounds__(256) void wlt_kernel(
    const float* __restrict__ wl, unsigned short* __restrict__ wlt) {
  __shared__ float tile[32][33];
  const int x0 = blockIdx.x * 32, y0 = blockIdx.y * 32;
  const int tx = threadIdx.x, ty = threadIdx.y;
  for (int i = ty; i < 32; i += 8) tile[i][tx] = wl[(size_t)(y0 + i) * H_ + x0 + tx];
  __syncthreads();
  for (int i = ty; i < 32; i += 8)
    wlt[(size_t)(x0 + i) * H_ + y0 + tx] = f2bf(tile[tx][i]);
}

// ---------------- gather selected rows, cast bf16 ----------------
__global__ __launch_bounds__(256) void gather_cast_kernel(
    const float* __restrict__ x, const int* __restrict__ comp,
    unsigned short* __restrict__ xg) {
  int tid = blockIdx.x * 256 + threadIdx.x;   // covers M_*H_/4
  int rowc = tid >> 8;                        // 256 float4 per row
  int c4 = tid & 255;
  int b = rowc >> 12, cc = rowc & (CAP_ - 1);
  int token = comp[b * CAP_ + cc];
  float4 v = *(const float4*)&x[((size_t)(b * S_ + token)) * H_ + c4 * 4];
  ushort4 o;
  o.x = f2bf(v.x); o.y = f2bf(v.y); o.z = f2bf(v.z); o.w = f2bf(v.w);
  *(ushort4*)&xg[(size_t)rowc * H_ + c4 * 4] = o;
}

// ---------------- main GEMM: out[selected] = gelu(xg @ WlT^T), bf16 MFMA ----------------
__global__ __launch_bounds__(256) void moe_gemm_kernel(
    const unsigned short* __restrict__ xg, const unsigned short* __restrict__ wlt,
    const int* __restrict__ comp, float* __restrict__ out) {
  __shared__ __align__(16) unsigned short As[128 * 32];
  __shared__ __align__(16) unsigned short Bs[128 * 32];
  __shared__ int toks[128];
  const int t = threadIdx.x;
  const int lane = t & 63, w = t >> 6;
  const int m0 = blockIdx.x * 128, n0 = blockIdx.y * 128;
  const int bb = m0 >> 12;                     // 128 | 4096 -> whole block in one batch
  if (t < 128) toks[t] = comp[bb * CAP_ + (m0 & (CAP_ - 1)) + t];
  const int wr = w >> 1, wc = w & 1;           // wave -> 64x64 quadrant
  const int r16 = lane & 15, ks = lane >> 4;

  f32x4 acc[4][4];
  #pragma unroll
  for (int i = 0; i < 4; ++i)
    #pragma unroll
    for (int j = 0; j < 4; ++j) acc[i][j] = (f32x4){0.f, 0.f, 0.f, 0.f};

  for (int k0 = 0; k0 < H_; k0 += 32) {
    #pragma unroll
    for (int q = 0; q < 2; ++q) {
      int c = q * 256 + w * 64 + lane;         // chunk id, 16B each
      int row = c >> 2, sl = c & 3;
      gload_lds16(&xg[(size_t)(m0 + row) * H_ + k0 + sl * 8], &As[(q * 256 + w * 64) * 8]);
      gload_lds16(&wlt[(size_t)(n0 + row) * H_ + k0 + sl * 8], &Bs[(q * 256 + w * 64) * 8]);
    }
    __syncthreads();
    s16x8 af[4], bfr[4];
    #pragma unroll
    for (int i = 0; i < 4; ++i)
      af[i] = *(const s16x8*)&As[(wr * 64 + i * 16 + r16) * 32 + ks * 8];
    #pragma unroll
    for (int j = 0; j < 4; ++j)
      bfr[j] = *(const s16x8*)&Bs[(wc * 64 + j * 16 + r16) * 32 + ks * 8];
    #pragma unroll
    for (int i = 0; i < 4; ++i)
      #pragma unroll
      for (int j = 0; j < 4; ++j)
        acc[i][j] = __builtin_amdgcn_mfma_f32_16x16x32_bf16(af[i], bfr[j], acc[i][j], 0, 0, 0);
    __syncthreads();
  }

  // epilogue: gelu + scatter to token rows
  #pragma unroll
  for (int i = 0; i < 4; ++i) {
    #pragma unroll
    for (int r = 0; r < 4; ++r) {
      int rl = wr * 64 + i * 16 + (lane >> 4) * 4 + r;   // C/D: row=(lane>>4)*4+reg
      int token = toks[rl];
      float* orow = out + ((size_t)(bb * S_ + token)) * H_ + n0 + wc * 64;
      #pragma unroll
      for (int j = 0; j < 4; ++j)
        orow[j * 16 + r16] = gelu_t(acc[i][j][r]);       // C/D: col=lane&15
    }
  }
}

extern "C" void kernel_launch(void* const* d_in, const int* in_sizes, int n_in,
                              void* d_out, int out_size, void* d_ws, size_t ws_size,
                              hipStream_t stream) {
  const float* x  = (const float*)d_in[0];
  const float* W1 = (const float*)d_in[1];
  const float* b1 = (const float*)d_in[2];
  const float* W2 = (const float*)d_in[3];
  const float* b2 = (const float*)d_in[4];
  const float* Wl = (const float*)d_in[5];
  float* out = (float*)d_out;
  float* rw  = out + (size_t)B_ * S_ * H_;

  char* ws = (char*)d_ws;
  float* scores        = (float*)ws;                                   // 256 KB
  int*   comp          = (int*)(ws + (256 << 10));                     // 128 KB
  unsigned short* wlt  = (unsigned short*)(ws + (512 << 10));          // 2 MB
  unsigned short* xg   = (unsigned short*)(ws + (512 << 10) + (2 << 20)); // 64 MB

  // unselected rows: straight copy (overwritten for selected rows by GEMM)
  hipMemcpyAsync(out, x, (size_t)B_ * S_ * H_ * sizeof(float),
                 hipMemcpyDeviceToDevice, stream);
  hipLaunchKernelGGL(router_kernel, dim3((B_*S_)/64), dim3(256), 0, stream,
                     x, W1, b1, W2, b2, scores, rw);
  hipLaunchKernelGGL(topk_kernel, dim3(B_), dim3(1024), 0, stream, scores, comp);
  hipLaunchKernelGGL(wlt_kernel, dim3(H_/32, H_/32), dim3(32, 8), 0, stream, Wl, wlt);
  hipLaunchKernelGGL(gather_cast_kernel, dim3(M_*H_/4/256), dim3(256), 0, stream,
                     x, comp, xg);
  hipLaunchKernelGGL(moe_gemm_kernel, dim3(M_/128, H_/128), dim3(256), 0, stream,
                     xg, wlt, comp, out);
}

// Round 2
// 548.021 us; speedup vs baseline: 1.2919x; 1.2919x over previous
//
#include <hip/hip_runtime.h>
#include <stdint.h>

#define B_   8
#define S_   8192
#define H_   1024
#define HQ_  256
#define CAP_ 4096
#define M_   (B_*CAP_)   // 32768
#define EPSB 2e-3f
#define LCAP 8192

using f32x4 = __attribute__((ext_vector_type(4))) float;
using s16x8 = __attribute__((ext_vector_type(8))) short;

__device__ __forceinline__ unsigned short f2bf(float f) {
  unsigned u = __float_as_uint(f);
  u += 0x7FFF + ((u >> 16) & 1);   // RNE
  return (unsigned short)(u >> 16);
}
__device__ __forceinline__ float bf2f(unsigned short h) {
  return __uint_as_float(((unsigned)h) << 16);
}

__device__ __forceinline__ float gelu_t(float v) {
  float z = 0.7978845608028654f * (v + 0.044715f * v * v * v);
  return 0.5f * v * (1.0f + tanhf(z));
}

__device__ __forceinline__ void gload_lds16(const void* g, void* l) {
  __builtin_amdgcn_global_load_lds(
      (const __attribute__((address_space(1))) void*)(uintptr_t)g,
      (__attribute__((address_space(3))) void*)(uintptr_t)l,
      16, 0, 0);
}

// ---------------- W1 -> transposed bf16 hi/lo split ----------------
__global__ __launch_bounds__(256) void prep_w1_kernel(
    const float* __restrict__ W1, unsigned short* __restrict__ w1t_hi,
    unsigned short* __restrict__ w1t_lo) {
  __shared__ float tile[32][33];
  const int n0 = blockIdx.x * 32, k0 = blockIdx.y * 32;
  const int tx = threadIdx.x, ty = threadIdx.y;
  for (int i = ty; i < 32; i += 8) tile[i][tx] = W1[(size_t)(k0 + i) * HQ_ + n0 + tx];
  __syncthreads();
  for (int i = ty; i < 32; i += 8) {
    float v = tile[tx][i];                 // = W1[k0+tx][n0+i]
    unsigned short h = f2bf(v);
    w1t_hi[(size_t)(n0 + i) * H_ + k0 + tx] = h;
    w1t_lo[(size_t)(n0 + i) * H_ + k0 + tx] = f2bf(v - bf2f(h));
  }
}

// ---------------- Router GEMM: split-bf16 MFMA, fused relu/W2 epilogue --------
// BM=128, BN=256(=N), BK=32, 8 waves. scores[m] = relu(x@W1+b1)@W2+b2 (approx).
__global__ __launch_bounds__(512) void router_mfma_kernel(
    const float* __restrict__ x, const unsigned short* __restrict__ w1t_hi,
    const unsigned short* __restrict__ w1t_lo, const float* __restrict__ b1,
    const float* __restrict__ W2, const float* __restrict__ b2,
    float* __restrict__ scores) {
  __shared__ __align__(16) unsigned short AsH[128 * 32];
  __shared__ __align__(16) unsigned short AsL[128 * 32];
  __shared__ __align__(16) unsigned short BsH[256 * 32];
  __shared__ __align__(16) unsigned short BsL[256 * 32];
  __shared__ float part[128][4];
  const int t = threadIdx.x;
  const int lane = t & 63, w = t >> 6;
  const int m0 = blockIdx.x * 128;
  const int wr = w >> 2, wc = w & 3;       // wave tile: rows wr*64, cols wc*64
  const int r16 = lane & 15, ks = lane >> 4;

  f32x4 acc[4][4];
  #pragma unroll
  for (int i = 0; i < 4; ++i)
    #pragma unroll
    for (int j = 0; j < 4; ++j) acc[i][j] = (f32x4){0.f, 0.f, 0.f, 0.f};

  for (int k0 = 0; k0 < H_; k0 += 32) {
    // A: reg-stage fp32 -> split into hi/lo bf16 LDS tiles
    #pragma unroll
    for (int u = 0; u < 2; ++u) {
      int idx = t + u * 512;
      int row = idx >> 3, q = idx & 7;
      float4 v = *(const float4*)&x[(size_t)(m0 + row) * H_ + k0 + q * 4];
      ushort4 hh, ll;
      hh.x = f2bf(v.x); ll.x = f2bf(v.x - bf2f(hh.x));
      hh.y = f2bf(v.y); ll.y = f2bf(v.y - bf2f(hh.y));
      hh.z = f2bf(v.z); ll.z = f2bf(v.z - bf2f(hh.z));
      hh.w = f2bf(v.w); ll.w = f2bf(v.w - bf2f(hh.w));
      *(ushort4*)&AsH[row * 32 + q * 4] = hh;
      *(ushort4*)&AsL[row * 32 + q * 4] = ll;
    }
    // B: direct global->LDS (w1t is bf16 [n][k], L2-resident)
    #pragma unroll
    for (int q = 0; q < 2; ++q) {
      int c0 = (q * 8 + w) * 64;
      int g = c0 + lane;
      int row = g >> 2, sl = g & 3;
      gload_lds16(&w1t_hi[(size_t)row * H_ + k0 + sl * 8], &BsH[c0 * 8]);
      gload_lds16(&w1t_lo[(size_t)row * H_ + k0 + sl * 8], &BsL[c0 * 8]);
    }
    __syncthreads();
    s16x8 ah[4], al[4], bh[4], bl[4];
    #pragma unroll
    for (int i = 0; i < 4; ++i) {
      ah[i] = *(const s16x8*)&AsH[(wr * 64 + i * 16 + r16) * 32 + ks * 8];
      al[i] = *(const s16x8*)&AsL[(wr * 64 + i * 16 + r16) * 32 + ks * 8];
    }
    #pragma unroll
    for (int j = 0; j < 4; ++j) {
      bh[j] = *(const s16x8*)&BsH[(wc * 64 + j * 16 + r16) * 32 + ks * 8];
      bl[j] = *(const s16x8*)&BsL[(wc * 64 + j * 16 + r16) * 32 + ks * 8];
    }
    #pragma unroll
    for (int i = 0; i < 4; ++i)
      #pragma unroll
      for (int j = 0; j < 4; ++j) {
        acc[i][j] = __builtin_amdgcn_mfma_f32_16x16x32_bf16(ah[i], bh[j], acc[i][j], 0, 0, 0);
        acc[i][j] = __builtin_amdgcn_mfma_f32_16x16x32_bf16(ah[i], bl[j], acc[i][j], 0, 0, 0);
        acc[i][j] = __builtin_amdgcn_mfma_f32_16x16x32_bf16(al[i], bh[j], acc[i][j], 0, 0, 0);
      }
    __syncthreads();
  }

  // epilogue: relu(z+b1)*W2, reduce over n
  float b1v[4], w2v[4];
  #pragma unroll
  for (int j = 0; j < 4; ++j) {
    int n = wc * 64 + j * 16 + r16;        // C/D col = lane&15
    b1v[j] = b1[n]; w2v[j] = W2[n];
  }
  const int g4 = lane >> 4;
  #pragma unroll
  for (int i = 0; i < 4; ++i) {
    #pragma unroll
    for (int r = 0; r < 4; ++r) {
      float p = 0.f;
      #pragma unroll
      for (int j = 0; j < 4; ++j) {
        float h = acc[i][j][r] + b1v[j];
        h = fmaxf(h, 0.f);
        p = fmaf(h, w2v[j], p);
      }
      p += __shfl_xor(p, 1);
      p += __shfl_xor(p, 2);
      p += __shfl_xor(p, 4);
      p += __shfl_xor(p, 8);
      if (r16 == 0) part[wr * 64 + i * 16 + g4 * 4 + r][wc] = p;
    }
  }
  __syncthreads();
  if (t < 128)
    scores[m0 + t] = part[t][0] + part[t][1] + part[t][2] + part[t][3] + b2[0];
}

// ---------------- bitonic sort: threshold out; optional stable compaction ----
__global__ __launch_bounds__(1024) void sort_kernel(
    const float* __restrict__ scores, float* __restrict__ thr,
    int* __restrict__ comp, int do_compact) {
  __shared__ float sv[S_];
  __shared__ int warp_cnt[16];
  const int b = blockIdx.x;
  const int tid = threadIdx.x;
  const float* srow = scores + (size_t)b * S_;
  for (int i = tid; i < S_; i += 1024) sv[i] = srow[i];
  __syncthreads();
  for (int k = 2; k <= S_; k <<= 1) {
    for (int j = k >> 1; j > 0; j >>= 1) {
      for (int tt = tid; tt < S_/2; tt += 1024) {
        int i = ((tt & ~(j - 1)) << 1) | (tt & (j - 1));
        int ixj = i + j;
        bool up = ((i & k) == 0);
        float a = sv[i], c = sv[ixj];
        if ((a > c) == up) { sv[i] = c; sv[ixj] = a; }
      }
      __syncthreads();
    }
  }
  const float T = sv[S_ - CAP_];
  if (tid == 0) thr[b] = T;
  if (!do_compact) return;

  int* crow = comp + b * CAP_;
  const int lane = tid & 63, wid = tid >> 6;
  int base = 0;
  for (int chunk = 0; chunk < S_/1024; ++chunk) {
    int idx = chunk * 1024 + tid;
    float s = srow[idx];
    bool f = s > T;
    unsigned long long m = __ballot(f);
    if (lane == 0) warp_cnt[wid] = __popcll(m);
    __syncthreads();
    int off = base; for (int w2 = 0; w2 < wid; ++w2) off += warp_cnt[w2];
    int tot = 0;    for (int w2 = 0; w2 < 16;  ++w2) tot += warp_cnt[w2];
    if (f) crow[off + __popcll(m & ((1ull << lane) - 1))] = idx;
    base += tot;
    __syncthreads();
  }
  const int cnt_gt = base;
  const int need = CAP_ - cnt_gt;
  int base2 = 0;
  for (int chunk = 0; chunk < S_/1024 && base2 < need; ++chunk) {
    int idx = chunk * 1024 + tid;
    float s = srow[idx];
    bool f = (s == T);
    unsigned long long m = __ballot(f);
    if (lane == 0) warp_cnt[wid] = __popcll(m);
    __syncthreads();
    int off = base2; for (int w2 = 0; w2 < wid; ++w2) off += warp_cnt[w2];
    int tot = 0;     for (int w2 = 0; w2 < 16;  ++w2) tot += warp_cnt[w2];
    int pos = off + __popcll(m & ((1ull << lane) - 1));
    if (f && pos < need) crow[cnt_gt + pos] = idx;
    base2 += tot;
    __syncthreads();
  }
}

// ---------------- band flag: tokens near threshold ----------------
__global__ __launch_bounds__(256) void band_kernel(
    const float* __restrict__ scores, const float* __restrict__ thr,
    int* __restrict__ list, int* __restrict__ count) {
  int i = blockIdx.x * 256 + threadIdx.x;
  float s = scores[i];
  int b = i >> 13;
  if (fabsf(s - thr[b]) <= EPSB) {
    int p = atomicAdd(count, 1);
    if (p < LCAP) list[p] = i;
  }
}

// ---------------- exact fp32 score recompute for band tokens ----------------
__global__ __launch_bounds__(256) void recompute_kernel(
    const float* __restrict__ x, const float* __restrict__ W1,
    const float* __restrict__ b1, const float* __restrict__ W2,
    const float* __restrict__ b2, const int* __restrict__ list,
    const int* __restrict__ count, float* __restrict__ scores) {
  __shared__ float xr[H_];
  __shared__ float red[4];
  int n = *count; if (n > LCAP) n = LCAP;
  const int j = threadIdx.x;
  for (int li = blockIdx.x; li < n; li += gridDim.x) {
    int tok = list[li];
    const float* xrow = x + (size_t)tok * H_;
    for (int k = j; k < H_; k += 256) xr[k] = xrow[k];
    __syncthreads();
    float a = 0.f;
    for (int k = 0; k < H_; ++k) a = fmaf(xr[k], W1[(size_t)k * HQ_ + j], a);
    float h = fmaxf(a + b1[j], 0.f);
    float v = h * W2[j];
    v += __shfl_xor(v, 1);  v += __shfl_xor(v, 2);  v += __shfl_xor(v, 4);
    v += __shfl_xor(v, 8);  v += __shfl_xor(v, 16); v += __shfl_xor(v, 32);
    if ((j & 63) == 0) red[j >> 6] = v;
    __syncthreads();
    if (j == 0) scores[tok] = red[0] + red[1] + red[2] + red[3] + b2[0];
    __syncthreads();
  }
}

// ---------------- routing weights ----------------
__global__ __launch_bounds__(256) void rw_kernel(
    const float* __restrict__ scores, float* __restrict__ rw) {
  int i = blockIdx.x * 256 + threadIdx.x;
  rw[i] = 1.f / (1.f + expf(-scores[i]));
}

// ---------------- Wl -> WlT (bf16, transposed) ----------------
__global__ __launch_bounds__(256) void wlt_kernel(
    const float* __restrict__ wl, unsigned short* __restrict__ wlt) {
  __shared__ float tile[32][33];
  const int x0 = blockIdx.x * 32, y0 = blockIdx.y * 32;
  const int tx = threadIdx.x, ty = threadIdx.y;
  for (int i = ty; i < 32; i += 8) tile[i][tx] = wl[(size_t)(y0 + i) * H_ + x0 + tx];
  __syncthreads();
  for (int i = ty; i < 32; i += 8)
    wlt[(size_t)(x0 + i) * H_ + y0 + tx] = f2bf(tile[tx][i]);
}

// ---------------- gather selected rows, cast bf16 ----------------
__global__ __launch_bounds__(256) void gather_cast_kernel(
    const float* __restrict__ x, const int* __restrict__ comp,
    unsigned short* __restrict__ xg) {
  int tid = blockIdx.x * 256 + threadIdx.x;
  int rowc = tid >> 8;
  int c4 = tid & 255;
  int b = rowc >> 12, cc = rowc & (CAP_ - 1);
  int token = comp[b * CAP_ + cc];
  float4 v = *(const float4*)&x[((size_t)(b * S_ + token)) * H_ + c4 * 4];
  ushort4 o;
  o.x = f2bf(v.x); o.y = f2bf(v.y); o.z = f2bf(v.z); o.w = f2bf(v.w);
  *(ushort4*)&xg[(size_t)rowc * H_ + c4 * 4] = o;
}

// ---------------- main GEMM: out[selected] = gelu(xg @ WlT^T), bf16 MFMA ------
__global__ __launch_bounds__(256) void moe_gemm_kernel(
    const unsigned short* __restrict__ xg, const unsigned short* __restrict__ wlt,
    const int* __restrict__ comp, float* __restrict__ out) {
  __shared__ __align__(16) unsigned short As[128 * 32];
  __shared__ __align__(16) unsigned short Bs[128 * 32];
  __shared__ int toks[128];
  const int t = threadIdx.x;
  const int lane = t & 63, w = t >> 6;
  const int m0 = blockIdx.x * 128, n0 = blockIdx.y * 128;
  const int bb = m0 >> 12;
  if (t < 128) toks[t] = comp[bb * CAP_ + (m0 & (CAP_ - 1)) + t];
  const int wr = w >> 1, wc = w & 1;
  const int r16 = lane & 15, ks = lane >> 4;

  f32x4 acc[4][4];
  #pragma unroll
  for (int i = 0; i < 4; ++i)
    #pragma unroll
    for (int j = 0; j < 4; ++j) acc[i][j] = (f32x4){0.f, 0.f, 0.f, 0.f};

  for (int k0 = 0; k0 < H_; k0 += 32) {
    #pragma unroll
    for (int q = 0; q < 2; ++q) {
      int c = q * 256 + w * 64 + lane;
      int row = c >> 2, sl = c & 3;
      gload_lds16(&xg[(size_t)(m0 + row) * H_ + k0 + sl * 8], &As[(q * 256 + w * 64) * 8]);
      gload_lds16(&wlt[(size_t)(n0 + row) * H_ + k0 + sl * 8], &Bs[(q * 256 + w * 64) * 8]);
    }
    __syncthreads();
    s16x8 af[4], bfr[4];
    #pragma unroll
    for (int i = 0; i < 4; ++i)
      af[i] = *(const s16x8*)&As[(wr * 64 + i * 16 + r16) * 32 + ks * 8];
    #pragma unroll
    for (int j = 0; j < 4; ++j)
      bfr[j] = *(const s16x8*)&Bs[(wc * 64 + j * 16 + r16) * 32 + ks * 8];
    #pragma unroll
    for (int i = 0; i < 4; ++i)
      #pragma unroll
      for (int j = 0; j < 4; ++j)
        acc[i][j] = __builtin_amdgcn_mfma_f32_16x16x32_bf16(af[i], bfr[j], acc[i][j], 0, 0, 0);
    __syncthreads();
  }

  #pragma unroll
  for (int i = 0; i < 4; ++i) {
    #pragma unroll
    for (int r = 0; r < 4; ++r) {
      int rl = wr * 64 + i * 16 + (lane >> 4) * 4 + r;
      int token = toks[rl];
      float* orow = out + ((size_t)(bb * S_ + token)) * H_ + n0 + wc * 64;
      #pragma unroll
      for (int j = 0; j < 4; ++j)
        orow[j * 16 + r16] = gelu_t(acc[i][j][r]);
    }
  }
}

extern "C" void kernel_launch(void* const* d_in, const int* in_sizes, int n_in,
                              void* d_out, int out_size, void* d_ws, size_t ws_size,
                              hipStream_t stream) {
  const float* x  = (const float*)d_in[0];
  const float* W1 = (const float*)d_in[1];
  const float* b1 = (const float*)d_in[2];
  const float* W2 = (const float*)d_in[3];
  const float* b2 = (const float*)d_in[4];
  const float* Wl = (const float*)d_in[5];
  float* out = (float*)d_out;
  float* rw  = out + (size_t)B_ * S_ * H_;

  char* ws = (char*)d_ws;
  float* scores        = (float*)ws;                                 // 256 KB
  int*   comp          = (int*)(ws + (256 << 10));                   // 128 KB
  float* thr           = (float*)(ws + (384 << 10));                 // 32 B
  int*   count         = (int*)(ws + (384 << 10) + 256);             // 4 B
  int*   list          = (int*)(ws + (384 << 10) + 512);             // 32 KB
  unsigned short* wlt  = (unsigned short*)(ws + (512 << 10));        // 2 MB
  unsigned short* xg   = (unsigned short*)(ws + (512 << 10) + (2 << 20)); // 64 MB
  // w1t hi/lo overlap the head of xg: dead before gather_cast writes xg
  unsigned short* w1t_hi = xg;               // 512 KB
  unsigned short* w1t_lo = xg + 262144;      // 512 KB

  hipMemsetAsync(count, 0, sizeof(int), stream);
  hipMemcpyAsync(out, x, (size_t)B_ * S_ * H_ * sizeof(float),
                 hipMemcpyDeviceToDevice, stream);
  hipLaunchKernelGGL(prep_w1_kernel, dim3(HQ_/32, H_/32), dim3(32, 8), 0, stream,
                     W1, w1t_hi, w1t_lo);
  hipLaunchKernelGGL(router_mfma_kernel, dim3((B_*S_)/128), dim3(512), 0, stream,
                     x, w1t_hi, w1t_lo, b1, W2, b2, scores);
  hipLaunchKernelGGL(sort_kernel, dim3(B_), dim3(1024), 0, stream,
                     scores, thr, comp, 0);
  hipLaunchKernelGGL(band_kernel, dim3((B_*S_)/256), dim3(256), 0, stream,
                     scores, thr, list, count);
  hipLaunchKernelGGL(recompute_kernel, dim3(128), dim3(256), 0, stream,
                     x, W1, b1, W2, b2, list, count, scores);
  hipLaunchKernelGGL(sort_kernel, dim3(B_), dim3(1024), 0, stream,
                     scores, thr, comp, 1);
  hipLaunchKernelGGL(rw_kernel, dim3((B_*S_)/256), dim3(256), 0, stream,
                     scores, rw);
  hipLaunchKernelGGL(wlt_kernel, dim3(H_/32, H_/32), dim3(32, 8), 0, stream, Wl, wlt);
  hipLaunchKernelGGL(gather_cast_kernel, dim3(M_*H_/4/256), dim3(256), 0, stream,
                     x, comp, xg);
  hipLaunchKernelGGL(moe_gemm_kernel, dim3(M_/128, H_/128), dim3(256), 0, stream,
                     xg, wlt, comp, out);
}

// Round 3
// 515.925 us; speedup vs baseline: 1.3723x; 1.0622x over previous
//
#include <hip/hip_runtime.h>
#include <stdint.h>

#define B_   8
#define S_   8192
#define H_   1024
#define HQ_  256
#define CAP_ 4096
#define M_   (B_*CAP_)   // 32768
#define EPSB 2e-3f
#define LCAP 8192

using f32x4 = __attribute__((ext_vector_type(4))) float;
using s16x8 = __attribute__((ext_vector_type(8))) short;

__device__ __forceinline__ unsigned short f2bf(float f) {
  unsigned u = __float_as_uint(f);
  u += 0x7FFF + ((u >> 16) & 1);   // RNE
  return (unsigned short)(u >> 16);
}
__device__ __forceinline__ float bf2f(unsigned short h) {
  return __uint_as_float(((unsigned)h) << 16);
}

// gelu tanh-approx via hw exp: 0.5v(1+tanh(z)) == v * sigmoid(2z)
__device__ __forceinline__ float gelu_f(float v) {
  float s = v + 0.044715f * v * v * v;
  float e = __expf(-1.5957691216057308f * s);   // exp(-2*0.79788456*s)
  return v * __builtin_amdgcn_rcpf(1.0f + e);
}

__device__ __forceinline__ void gload_lds16(const void* g, void* l) {
  __builtin_amdgcn_global_load_lds(
      (const __attribute__((address_space(1))) void*)(uintptr_t)g,
      (__attribute__((address_space(3))) void*)(uintptr_t)l,
      16, 0, 0);
}

// ---------------- W1 -> transposed bf16 hi/lo split ----------------
__global__ __launch_bounds__(256) void prep_w1_kernel(
    const float* __restrict__ W1, unsigned short* __restrict__ w1t_hi,
    unsigned short* __restrict__ w1t_lo) {
  __shared__ float tile[32][33];
  const int n0 = blockIdx.x * 32, k0 = blockIdx.y * 32;
  const int tx = threadIdx.x, ty = threadIdx.y;
  for (int i = ty; i < 32; i += 8) tile[i][tx] = W1[(size_t)(k0 + i) * HQ_ + n0 + tx];
  __syncthreads();
  for (int i = ty; i < 32; i += 8) {
    float v = tile[tx][i];                 // = W1[k0+tx][n0+i]
    unsigned short h = f2bf(v);
    w1t_hi[(size_t)(n0 + i) * H_ + k0 + tx] = h;
    w1t_lo[(size_t)(n0 + i) * H_ + k0 + tx] = f2bf(v - bf2f(h));
  }
}

// ---------------- Router GEMM: split-bf16 MFMA, fused relu/W2 epilogue --------
__global__ __launch_bounds__(512) void router_mfma_kernel(
    const float* __restrict__ x, const unsigned short* __restrict__ w1t_hi,
    const unsigned short* __restrict__ w1t_lo, const float* __restrict__ b1,
    const float* __restrict__ W2, const float* __restrict__ b2,
    float* __restrict__ scores) {
  __shared__ __align__(16) unsigned short AsH[128 * 32];
  __shared__ __align__(16) unsigned short AsL[128 * 32];
  __shared__ __align__(16) unsigned short BsH[256 * 32];
  __shared__ __align__(16) unsigned short BsL[256 * 32];
  __shared__ float part[128][4];
  const int t = threadIdx.x;
  const int lane = t & 63, w = t >> 6;
  const int m0 = blockIdx.x * 128;
  const int wr = w >> 2, wc = w & 3;
  const int r16 = lane & 15, ks = lane >> 4;

  f32x4 acc[4][4];
  #pragma unroll
  for (int i = 0; i < 4; ++i)
    #pragma unroll
    for (int j = 0; j < 4; ++j) acc[i][j] = (f32x4){0.f, 0.f, 0.f, 0.f};

  for (int k0 = 0; k0 < H_; k0 += 32) {
    #pragma unroll
    for (int u = 0; u < 2; ++u) {
      int idx = t + u * 512;
      int row = idx >> 3, q = idx & 7;
      float4 v = *(const float4*)&x[(size_t)(m0 + row) * H_ + k0 + q * 4];
      ushort4 hh, ll;
      hh.x = f2bf(v.x); ll.x = f2bf(v.x - bf2f(hh.x));
      hh.y = f2bf(v.y); ll.y = f2bf(v.y - bf2f(hh.y));
      hh.z = f2bf(v.z); ll.z = f2bf(v.z - bf2f(hh.z));
      hh.w = f2bf(v.w); ll.w = f2bf(v.w - bf2f(hh.w));
      *(ushort4*)&AsH[row * 32 + q * 4] = hh;
      *(ushort4*)&AsL[row * 32 + q * 4] = ll;
    }
    #pragma unroll
    for (int q = 0; q < 2; ++q) {
      int c0 = (q * 8 + w) * 64;
      int g = c0 + lane;
      int row = g >> 2, sl = g & 3;
      gload_lds16(&w1t_hi[(size_t)row * H_ + k0 + sl * 8], &BsH[c0 * 8]);
      gload_lds16(&w1t_lo[(size_t)row * H_ + k0 + sl * 8], &BsL[c0 * 8]);
    }
    __syncthreads();
    s16x8 ah[4], al[4], bh[4], bl[4];
    #pragma unroll
    for (int i = 0; i < 4; ++i) {
      ah[i] = *(const s16x8*)&AsH[(wr * 64 + i * 16 + r16) * 32 + ks * 8];
      al[i] = *(const s16x8*)&AsL[(wr * 64 + i * 16 + r16) * 32 + ks * 8];
    }
    #pragma unroll
    for (int j = 0; j < 4; ++j) {
      bh[j] = *(const s16x8*)&BsH[(wc * 64 + j * 16 + r16) * 32 + ks * 8];
      bl[j] = *(const s16x8*)&BsL[(wc * 64 + j * 16 + r16) * 32 + ks * 8];
    }
    #pragma unroll
    for (int i = 0; i < 4; ++i)
      #pragma unroll
      for (int j = 0; j < 4; ++j) {
        acc[i][j] = __builtin_amdgcn_mfma_f32_16x16x32_bf16(ah[i], bh[j], acc[i][j], 0, 0, 0);
        acc[i][j] = __builtin_amdgcn_mfma_f32_16x16x32_bf16(ah[i], bl[j], acc[i][j], 0, 0, 0);
        acc[i][j] = __builtin_amdgcn_mfma_f32_16x16x32_bf16(al[i], bh[j], acc[i][j], 0, 0, 0);
      }
    __syncthreads();
  }

  float b1v[4], w2v[4];
  #pragma unroll
  for (int j = 0; j < 4; ++j) {
    int n = wc * 64 + j * 16 + r16;
    b1v[j] = b1[n]; w2v[j] = W2[n];
  }
  const int g4 = lane >> 4;
  #pragma unroll
  for (int i = 0; i < 4; ++i) {
    #pragma unroll
    for (int r = 0; r < 4; ++r) {
      float p = 0.f;
      #pragma unroll
      for (int j = 0; j < 4; ++j) {
        float h = acc[i][j][r] + b1v[j];
        h = fmaxf(h, 0.f);
        p = fmaf(h, w2v[j], p);
      }
      p += __shfl_xor(p, 1);
      p += __shfl_xor(p, 2);
      p += __shfl_xor(p, 4);
      p += __shfl_xor(p, 8);
      if (r16 == 0) part[wr * 64 + i * 16 + g4 * 4 + r][wc] = p;
    }
  }
  __syncthreads();
  if (t < 128)
    scores[m0 + t] = part[t][0] + part[t][1] + part[t][2] + part[t][3] + b2[0];
}

// ---------------- bitonic sort: threshold out; optional stable compaction ----
__global__ __launch_bounds__(1024) void sort_kernel(
    const float* __restrict__ scores, float* __restrict__ thr,
    int* __restrict__ comp, int do_compact) {
  __shared__ float sv[S_];
  __shared__ int warp_cnt[16];
  const int b = blockIdx.x;
  const int tid = threadIdx.x;
  const float* srow = scores + (size_t)b * S_;
  for (int i = tid; i < S_; i += 1024) sv[i] = srow[i];
  __syncthreads();
  for (int k = 2; k <= S_; k <<= 1) {
    for (int j = k >> 1; j > 0; j >>= 1) {
      for (int tt = tid; tt < S_/2; tt += 1024) {
        int i = ((tt & ~(j - 1)) << 1) | (tt & (j - 1));
        int ixj = i + j;
        bool up = ((i & k) == 0);
        float a = sv[i], c = sv[ixj];
        if ((a > c) == up) { sv[i] = c; sv[ixj] = a; }
      }
      __syncthreads();
    }
  }
  const float T = sv[S_ - CAP_];
  if (tid == 0) thr[b] = T;
  if (!do_compact) return;

  int* crow = comp + b * CAP_;
  const int lane = tid & 63, wid = tid >> 6;
  int base = 0;
  for (int chunk = 0; chunk < S_/1024; ++chunk) {
    int idx = chunk * 1024 + tid;
    float s = srow[idx];
    bool f = s > T;
    unsigned long long m = __ballot(f);
    if (lane == 0) warp_cnt[wid] = __popcll(m);
    __syncthreads();
    int off = base; for (int w2 = 0; w2 < wid; ++w2) off += warp_cnt[w2];
    int tot = 0;    for (int w2 = 0; w2 < 16;  ++w2) tot += warp_cnt[w2];
    if (f) crow[off + __popcll(m & ((1ull << lane) - 1))] = idx;
    base += tot;
    __syncthreads();
  }
  const int cnt_gt = base;
  const int need = CAP_ - cnt_gt;
  int base2 = 0;
  for (int chunk = 0; chunk < S_/1024 && base2 < need; ++chunk) {
    int idx = chunk * 1024 + tid;
    float s = srow[idx];
    bool f = (s == T);
    unsigned long long m = __ballot(f);
    if (lane == 0) warp_cnt[wid] = __popcll(m);
    __syncthreads();
    int off = base2; for (int w2 = 0; w2 < wid; ++w2) off += warp_cnt[w2];
    int tot = 0;     for (int w2 = 0; w2 < 16;  ++w2) tot += warp_cnt[w2];
    int pos = off + __popcll(m & ((1ull << lane) - 1));
    if (f && pos < need) crow[cnt_gt + pos] = idx;
    base2 += tot;
    __syncthreads();
  }
}

// ---------------- band flag: tokens near threshold ----------------
__global__ __launch_bounds__(256) void band_kernel(
    const float* __restrict__ scores, const float* __restrict__ thr,
    int* __restrict__ list, int* __restrict__ count) {
  int i = blockIdx.x * 256 + threadIdx.x;
  float s = scores[i];
  int b = i >> 13;
  if (fabsf(s - thr[b]) <= EPSB) {
    int p = atomicAdd(count, 1);
    if (p < LCAP) list[p] = i;
  }
}

// ---------------- exact fp32 score recompute for band tokens ----------------
__global__ __launch_bounds__(256) void recompute_kernel(
    const float* __restrict__ x, const float* __restrict__ W1,
    const float* __restrict__ b1, const float* __restrict__ W2,
    const float* __restrict__ b2, const int* __restrict__ list,
    const int* __restrict__ count, float* __restrict__ scores) {
  __shared__ float xr[H_];
  __shared__ float red[4];
  int n = *count; if (n > LCAP) n = LCAP;
  const int j = threadIdx.x;
  for (int li = blockIdx.x; li < n; li += gridDim.x) {
    int tok = list[li];
    const float* xrow = x + (size_t)tok * H_;
    for (int k = j; k < H_; k += 256) xr[k] = xrow[k];
    __syncthreads();
    float a = 0.f;
    for (int k = 0; k < H_; ++k) a = fmaf(xr[k], W1[(size_t)k * HQ_ + j], a);
    float h = fmaxf(a + b1[j], 0.f);
    float v = h * W2[j];
    v += __shfl_xor(v, 1);  v += __shfl_xor(v, 2);  v += __shfl_xor(v, 4);
    v += __shfl_xor(v, 8);  v += __shfl_xor(v, 16); v += __shfl_xor(v, 32);
    if ((j & 63) == 0) red[j >> 6] = v;
    __syncthreads();
    if (j == 0) scores[tok] = red[0] + red[1] + red[2] + red[3] + b2[0];
    __syncthreads();
  }
}

// ---------------- routing weights ----------------
__global__ __launch_bounds__(256) void rw_kernel(
    const float* __restrict__ scores, float* __restrict__ rw) {
  int i = blockIdx.x * 256 + threadIdx.x;
  rw[i] = 1.f / (1.f + expf(-scores[i]));
}

// ---------------- selection flags + copy only unselected rows ----------------
__global__ __launch_bounds__(256) void flags_kernel(
    const int* __restrict__ comp, int* __restrict__ flags) {
  int i = blockIdx.x * 256 + threadIdx.x;   // over M_
  int b = i >> 12;
  flags[b * S_ + comp[i]] = 1;
}

__global__ __launch_bounds__(256) void copy_unsel_kernel(
    const float* __restrict__ x, const int* __restrict__ flags,
    float* __restrict__ out) {
  int row = blockIdx.x;
  if (flags[row]) return;
  const float4* src = (const float4*)(x + (size_t)row * H_);
  float4* dst = (float4*)(out + (size_t)row * H_);
  dst[threadIdx.x] = src[threadIdx.x];      // 256 * float4 = 1024 floats
}

// ---------------- Wl -> WlT (bf16, transposed) ----------------
__global__ __launch_bounds__(256) void wlt_kernel(
    const float* __restrict__ wl, unsigned short* __restrict__ wlt) {
  __shared__ float tile[32][33];
  const int x0 = blockIdx.x * 32, y0 = blockIdx.y * 32;
  const int tx = threadIdx.x, ty = threadIdx.y;
  for (int i = ty; i < 32; i += 8) tile[i][tx] = wl[(size_t)(y0 + i) * H_ + x0 + tx];
  __syncthreads();
  for (int i = ty; i < 32; i += 8)
    wlt[(size_t)(x0 + i) * H_ + y0 + tx] = f2bf(tile[tx][i]);
}

// ---------------- gather selected rows, cast bf16 ----------------
__global__ __launch_bounds__(256) void gather_cast_kernel(
    const float* __restrict__ x, const int* __restrict__ comp,
    unsigned short* __restrict__ xg) {
  int tid = blockIdx.x * 256 + threadIdx.x;
  int rowc = tid >> 8;
  int c4 = tid & 255;
  int b = rowc >> 12, cc = rowc & (CAP_ - 1);
  int token = comp[b * CAP_ + cc];
  float4 v = *(const float4*)&x[((size_t)(b * S_ + token)) * H_ + c4 * 4];
  ushort4 o;
  o.x = f2bf(v.x); o.y = f2bf(v.y); o.z = f2bf(v.z); o.w = f2bf(v.w);
  *(ushort4*)&xg[(size_t)rowc * H_ + c4 * 4] = o;
}

// ---------------- main GEMM: out[selected] = gelu(xg @ WlT^T) ----------------
// BK=64, XOR-swizzled LDS (swizzled per-lane gload source + swizzled ds_read).
__global__ __launch_bounds__(256) void moe_gemm_kernel(
    const unsigned short* __restrict__ xg, const unsigned short* __restrict__ wlt,
    const int* __restrict__ comp, float* __restrict__ out) {
  __shared__ __align__(16) unsigned short As[128 * 64];
  __shared__ __align__(16) unsigned short Bs[128 * 64];
  __shared__ int toks[128];
  const int t = threadIdx.x;
  const int lane = t & 63, w = t >> 6;
  const int m0 = blockIdx.x * 128, n0 = blockIdx.y * 128;
  const int bb = m0 >> 12;
  if (t < 128) toks[t] = comp[bb * CAP_ + (m0 & (CAP_ - 1)) + t];
  const int wr = w >> 1, wc = w & 1;
  const int r16 = lane & 15, ks = lane >> 4;

  // per-lane staging sources; chunk within row pre-XOR'd so the linear
  // global_load_lds write produces the swizzled LDS image (rule 21 / T2)
  const unsigned short* aS[4];
  const unsigned short* bS[4];
  #pragma unroll
  for (int u = 0; u < 4; ++u) {
    int c = u * 256 + t;
    int row = c >> 3, sl = c & 7;
    int slz = sl ^ (row & 7);
    aS[u] = xg + (size_t)(m0 + row) * H_ + slz * 8;
    bS[u] = wlt + (size_t)(n0 + row) * H_ + slz * 8;
  }

  f32x4 acc[4][4];
  #pragma unroll
  for (int i = 0; i < 4; ++i)
    #pragma unroll
    for (int j = 0; j < 4; ++j) acc[i][j] = (f32x4){0.f, 0.f, 0.f, 0.f};

  for (int k0 = 0; k0 < H_; k0 += 64) {
    #pragma unroll
    for (int u = 0; u < 4; ++u) {
      gload_lds16(aS[u] + k0, &As[(u * 256 + w * 64) * 8]);
      gload_lds16(bS[u] + k0, &Bs[(u * 256 + w * 64) * 8]);
    }
    __syncthreads();
    #pragma unroll
    for (int kk = 0; kk < 2; ++kk) {
      s16x8 af[4], bfr[4];
      const int g = kk * 4 + ks;           // wanted 16B chunk col
      #pragma unroll
      for (int i = 0; i < 4; ++i) {
        int r = wr * 64 + i * 16 + r16;
        af[i] = *(const s16x8*)&As[r * 64 + (g ^ (r & 7)) * 8];
      }
      #pragma unroll
      for (int j = 0; j < 4; ++j) {
        int r = wc * 64 + j * 16 + r16;
        bfr[j] = *(const s16x8*)&Bs[r * 64 + (g ^ (r & 7)) * 8];
      }
      #pragma unroll
      for (int i = 0; i < 4; ++i)
        #pragma unroll
        for (int j = 0; j < 4; ++j)
          acc[i][j] = __builtin_amdgcn_mfma_f32_16x16x32_bf16(af[i], bfr[j], acc[i][j], 0, 0, 0);
    }
    __syncthreads();
  }

  #pragma unroll
  for (int i = 0; i < 4; ++i) {
    #pragma unroll
    for (int r = 0; r < 4; ++r) {
      int rl = wr * 64 + i * 16 + (lane >> 4) * 4 + r;
      int token = toks[rl];
      float* orow = out + ((size_t)(bb * S_ + token)) * H_ + n0 + wc * 64;
      #pragma unroll
      for (int j = 0; j < 4; ++j)
        orow[j * 16 + r16] = gelu_f(acc[i][j][r]);
    }
  }
}

extern "C" void kernel_launch(void* const* d_in, const int* in_sizes, int n_in,
                              void* d_out, int out_size, void* d_ws, size_t ws_size,
                              hipStream_t stream) {
  const float* x  = (const float*)d_in[0];
  const float* W1 = (const float*)d_in[1];
  const float* b1 = (const float*)d_in[2];
  const float* W2 = (const float*)d_in[3];
  const float* b2 = (const float*)d_in[4];
  const float* Wl = (const float*)d_in[5];
  float* out = (float*)d_out;
  float* rw  = out + (size_t)B_ * S_ * H_;

  char* ws = (char*)d_ws;
  float* scores        = (float*)ws;                                 // 256 KB
  int*   comp          = (int*)(ws + (256 << 10));                   // 128 KB
  float* thr           = (float*)(ws + (384 << 10));                 // 32 B
  int*   count         = (int*)(ws + (384 << 10) + 256);             // 4 B
  int*   list          = (int*)(ws + (384 << 10) + 512);             // 32 KB
  int*   flags         = (int*)(ws + (512 << 10));                   // 256 KB
  unsigned short* wlt  = (unsigned short*)(ws + (1 << 20));          // 2 MB
  unsigned short* xg   = (unsigned short*)(ws + (3 << 20));          // 64 MB
  // w1t hi/lo overlap the head of xg: dead before gather_cast writes xg
  unsigned short* w1t_hi = xg;               // 512 KB
  unsigned short* w1t_lo = xg + 262144;      // 512 KB

  hipMemsetAsync(count, 0, sizeof(int), stream);
  hipMemsetAsync(flags, 0, (size_t)B_ * S_ * sizeof(int), stream);
  hipLaunchKernelGGL(prep_w1_kernel, dim3(HQ_/32, H_/32), dim3(32, 8), 0, stream,
                     W1, w1t_hi, w1t_lo);
  hipLaunchKernelGGL(router_mfma_kernel, dim3((B_*S_)/128), dim3(512), 0, stream,
                     x, w1t_hi, w1t_lo, b1, W2, b2, scores);
  hipLaunchKernelGGL(sort_kernel, dim3(B_), dim3(1024), 0, stream,
                     scores, thr, comp, 0);
  hipLaunchKernelGGL(band_kernel, dim3((B_*S_)/256), dim3(256), 0, stream,
                     scores, thr, list, count);
  hipLaunchKernelGGL(recompute_kernel, dim3(128), dim3(256), 0, stream,
                     x, W1, b1, W2, b2, list, count, scores);
  hipLaunchKernelGGL(sort_kernel, dim3(B_), dim3(1024), 0, stream,
                     scores, thr, comp, 1);
  hipLaunchKernelGGL(rw_kernel, dim3((B_*S_)/256), dim3(256), 0, stream,
                     scores, rw);
  hipLaunchKernelGGL(flags_kernel, dim3(M_/256), dim3(256), 0, stream,
                     comp, flags);
  hipLaunchKernelGGL(copy_unsel_kernel, dim3(B_*S_), dim3(256), 0, stream,
                     x, flags, out);
  hipLaunchKernelGGL(wlt_kernel, dim3(H_/32, H_/32), dim3(32, 8), 0, stream, Wl, wlt);
  hipLaunchKernelGGL(gather_cast_kernel, dim3(M_*H_/4/256), dim3(256), 0, stream,
                     x, comp, xg);
  hipLaunchKernelGGL(moe_gemm_kernel, dim3(M_/128, H_/128), dim3(256), 0, stream,
                     xg, wlt, comp, out);
}

// Round 4
// 425.795 us; speedup vs baseline: 1.6628x; 1.2117x over previous
//
#include <hip/hip_runtime.h>
#include <stdint.h>

#define B_   8
#define S_   8192
#define H_   1024
#define HQ_  256
#define CAP_ 4096
#define UCAP_ (S_-CAP_)
#define M_   (B_*CAP_)   // 32768
#define EPSB 2e-3f
#define LCAP 8192

using f32x4 = __attribute__((ext_vector_type(4))) float;
using s16x8 = __attribute__((ext_vector_type(8))) short;

__device__ __forceinline__ unsigned short f2bf(float f) {
  unsigned u = __float_as_uint(f);
  u += 0x7FFF + ((u >> 16) & 1);   // RNE
  return (unsigned short)(u >> 16);
}
__device__ __forceinline__ float bf2f(unsigned short h) {
  return __uint_as_float(((unsigned)h) << 16);
}

// gelu tanh-approx via hw exp: 0.5v(1+tanh(z)) == v * sigmoid(2z)
__device__ __forceinline__ float gelu_f(float v) {
  float s = v + 0.044715f * v * v * v;
  float e = __expf(-1.5957691216057308f * s);
  return v * __builtin_amdgcn_rcpf(1.0f + e);
}

// monotonic fp32 <-> u32 key
__device__ __forceinline__ unsigned mono(float f) {
  unsigned u = __float_as_uint(f);
  return (u & 0x80000000u) ? ~u : (u | 0x80000000u);
}
__device__ __forceinline__ float unmono(unsigned k) {
  unsigned u = (k & 0x80000000u) ? (k & 0x7fffffffu) : ~k;
  return __uint_as_float(u);
}

__device__ __forceinline__ void gload_lds16(const void* g, void* l) {
  __builtin_amdgcn_global_load_lds(
      (const __attribute__((address_space(1))) void*)(uintptr_t)g,
      (__attribute__((address_space(3))) void*)(uintptr_t)l,
      16, 0, 0);
}

// ---------------- W1 -> transposed bf16 hi/lo split ----------------
__global__ __launch_bounds__(256) void prep_w1_kernel(
    const float* __restrict__ W1, unsigned short* __restrict__ w1t_hi,
    unsigned short* __restrict__ w1t_lo) {
  __shared__ float tile[32][33];
  const int n0 = blockIdx.x * 32, k0 = blockIdx.y * 32;
  const int tx = threadIdx.x, ty = threadIdx.y;
  for (int i = ty; i < 32; i += 8) tile[i][tx] = W1[(size_t)(k0 + i) * HQ_ + n0 + tx];
  __syncthreads();
  for (int i = ty; i < 32; i += 8) {
    float v = tile[tx][i];
    unsigned short h = f2bf(v);
    w1t_hi[(size_t)(n0 + i) * H_ + k0 + tx] = h;
    w1t_lo[(size_t)(n0 + i) * H_ + k0 + tx] = f2bf(v - bf2f(h));
  }
}

// ---------------- Router GEMM: split-bf16 MFMA, swizzled LDS ----------------
__global__ __launch_bounds__(512) void router_mfma_kernel(
    const float* __restrict__ x, const unsigned short* __restrict__ w1t_hi,
    const unsigned short* __restrict__ w1t_lo, const float* __restrict__ b1,
    const float* __restrict__ W2, const float* __restrict__ b2,
    float* __restrict__ scores) {
  __shared__ __align__(16) unsigned short AsH[128 * 32];
  __shared__ __align__(16) unsigned short AsL[128 * 32];
  __shared__ __align__(16) unsigned short BsH[256 * 32];
  __shared__ __align__(16) unsigned short BsL[256 * 32];
  __shared__ float part[128][4];
  const int t = threadIdx.x;
  const int lane = t & 63, w = t >> 6;
  const int m0 = blockIdx.x * 128;
  const int wr = w >> 2, wc = w & 3;
  const int r16 = lane & 15, ks = lane >> 4;

  f32x4 acc[4][4];
  #pragma unroll
  for (int i = 0; i < 4; ++i)
    #pragma unroll
    for (int j = 0; j < 4; ++j) acc[i][j] = (f32x4){0.f, 0.f, 0.f, 0.f};

  for (int k0 = 0; k0 < H_; k0 += 32) {
    // A: reg-stage fp32 -> hi/lo bf16, swizzled 16B-chunk write
    #pragma unroll
    for (int u = 0; u < 2; ++u) {
      int idx = t + u * 512;
      int row = idx >> 3, q = idx & 7;
      float4 v = *(const float4*)&x[(size_t)(m0 + row) * H_ + k0 + q * 4];
      ushort4 hh, ll;
      hh.x = f2bf(v.x); ll.x = f2bf(v.x - bf2f(hh.x));
      hh.y = f2bf(v.y); ll.y = f2bf(v.y - bf2f(hh.y));
      hh.z = f2bf(v.z); ll.z = f2bf(v.z - bf2f(hh.z));
      hh.w = f2bf(v.w); ll.w = f2bf(v.w - bf2f(hh.w));
      int so = row * 32 + (((q >> 1) ^ (row & 3)) << 3) + (q & 1) * 4;
      *(ushort4*)&AsH[so] = hh;
      *(ushort4*)&AsL[so] = ll;
    }
    // B: gload_lds with pre-swizzled per-lane global source (rule 21)
    #pragma unroll
    for (int q = 0; q < 2; ++q) {
      int c0 = (q * 8 + w) * 64;
      int g = c0 + lane;
      int row = g >> 2, sl = g & 3;
      int slz = sl ^ (row & 3);
      gload_lds16(&w1t_hi[(size_t)row * H_ + k0 + slz * 8], &BsH[c0 * 8]);
      gload_lds16(&w1t_lo[(size_t)row * H_ + k0 + slz * 8], &BsL[c0 * 8]);
    }
    __syncthreads();
    s16x8 ah[4], al[4], bh[4], bl[4];
    #pragma unroll
    for (int i = 0; i < 4; ++i) {
      int r = wr * 64 + i * 16 + r16;
      int co = (ks ^ (r & 3)) * 8;
      ah[i] = *(const s16x8*)&AsH[r * 32 + co];
      al[i] = *(const s16x8*)&AsL[r * 32 + co];
    }
    #pragma unroll
    for (int j = 0; j < 4; ++j) {
      int r = wc * 64 + j * 16 + r16;
      int co = (ks ^ (r & 3)) * 8;
      bh[j] = *(const s16x8*)&BsH[r * 32 + co];
      bl[j] = *(const s16x8*)&BsL[r * 32 + co];
    }
    #pragma unroll
    for (int i = 0; i < 4; ++i)
      #pragma unroll
      for (int j = 0; j < 4; ++j) {
        acc[i][j] = __builtin_amdgcn_mfma_f32_16x16x32_bf16(ah[i], bh[j], acc[i][j], 0, 0, 0);
        acc[i][j] = __builtin_amdgcn_mfma_f32_16x16x32_bf16(ah[i], bl[j], acc[i][j], 0, 0, 0);
        acc[i][j] = __builtin_amdgcn_mfma_f32_16x16x32_bf16(al[i], bh[j], acc[i][j], 0, 0, 0);
      }
    __syncthreads();
  }

  float b1v[4], w2v[4];
  #pragma unroll
  for (int j = 0; j < 4; ++j) {
    int n = wc * 64 + j * 16 + r16;
    b1v[j] = b1[n]; w2v[j] = W2[n];
  }
  const int g4 = lane >> 4;
  #pragma unroll
  for (int i = 0; i < 4; ++i) {
    #pragma unroll
    for (int r = 0; r < 4; ++r) {
      float p = 0.f;
      #pragma unroll
      for (int j = 0; j < 4; ++j) {
        float h = acc[i][j][r] + b1v[j];
        h = fmaxf(h, 0.f);
        p = fmaf(h, w2v[j], p);
      }
      p += __shfl_xor(p, 1);
      p += __shfl_xor(p, 2);
      p += __shfl_xor(p, 4);
      p += __shfl_xor(p, 8);
      if (r16 == 0) part[wr * 64 + i * 16 + g4 * 4 + r][wc] = p;
    }
  }
  __syncthreads();
  if (t < 128)
    scores[m0 + t] = part[t][0] + part[t][1] + part[t][2] + part[t][3] + b2[0];
}

// ---------------- exact radix-select: T = CAP_-th largest per row ------------
__global__ __launch_bounds__(1024) void select_kernel(
    const float* __restrict__ scores, float* __restrict__ thr) {
  __shared__ unsigned hist[2048];
  __shared__ unsigned sh_b, sh_gt;
  const int b = blockIdx.x;
  const int tid = threadIdx.x;
  const float* srow = scores + (size_t)b * S_;
  unsigned prefix = 0; int plen = 0; unsigned rank = CAP_;
  #pragma unroll
  for (int round = 0; round < 3; ++round) {
    const int nb = (round < 2) ? 11 : 10;
    hist[tid] = 0; hist[tid + 1024] = 0;
    __syncthreads();
    for (int i = tid; i < S_; i += 1024) {
      unsigned k = mono(srow[i]);
      if (plen == 0 || (k >> (32 - plen)) == prefix) {
        unsigned bucket = (k << plen) >> (32 - nb);
        atomicAdd(&hist[bucket], 1u);
      }
    }
    __syncthreads();
    // in-place suffix sum over 2048
    for (int s = 1; s < 2048; s <<= 1) {
      unsigned t0 = (tid + s < 2048) ? hist[tid + s] : 0;
      unsigned t1 = (tid + 1024 + s < 2048) ? hist[tid + 1024 + s] : 0;
      __syncthreads();
      hist[tid] += t0; hist[tid + 1024] += t1;
      __syncthreads();
    }
    // find bucket: gt < rank <= ge
    #pragma unroll
    for (int h = 0; h < 2; ++h) {
      int i = tid + h * 1024;
      unsigned ge = hist[i];
      unsigned gt = (i < 2047) ? hist[i + 1] : 0;
      if (gt < rank && rank <= ge) { sh_b = (unsigned)i; sh_gt = gt; }
    }
    __syncthreads();
    prefix = (prefix << nb) | sh_b;
    plen += nb;
    rank -= sh_gt;
    __syncthreads();
  }
  if (tid == 0) thr[b] = unmono(prefix);
}

// ---------------- band flag: tokens near threshold ----------------
__global__ __launch_bounds__(256) void band_kernel(
    const float* __restrict__ scores, const float* __restrict__ thr,
    int* __restrict__ list, int* __restrict__ count) {
  int i = blockIdx.x * 256 + threadIdx.x;
  float s = scores[i];
  int b = i >> 13;
  if (fabsf(s - thr[b]) <= EPSB) {
    int p = atomicAdd(count, 1);
    if (p < LCAP) list[p] = i;
  }
}

// ---------------- exact fp32 score recompute for band tokens ----------------
__global__ __launch_bounds__(256) void recompute_kernel(
    const float* __restrict__ x, const float* __restrict__ W1,
    const float* __restrict__ b1, const float* __restrict__ W2,
    const float* __restrict__ b2, const int* __restrict__ list,
    const int* __restrict__ count, float* __restrict__ scores) {
  __shared__ float xr[H_];
  __shared__ float red[4];
  int n = *count; if (n > LCAP) n = LCAP;
  const int j = threadIdx.x;
  for (int li = blockIdx.x; li < n; li += gridDim.x) {
    int tok = list[li];
    const float* xrow = x + (size_t)tok * H_;
    for (int k = j; k < H_; k += 256) xr[k] = xrow[k];
    __syncthreads();
    float a = 0.f;
    for (int k = 0; k < H_; ++k) a = fmaf(xr[k], W1[(size_t)k * HQ_ + j], a);
    float h = fmaxf(a + b1[j], 0.f);
    float v = h * W2[j];
    v += __shfl_xor(v, 1);  v += __shfl_xor(v, 2);  v += __shfl_xor(v, 4);
    v += __shfl_xor(v, 8);  v += __shfl_xor(v, 16); v += __shfl_xor(v, 32);
    if ((j & 63) == 0) red[j >> 6] = v;
    __syncthreads();
    if (j == 0) scores[tok] = red[0] + red[1] + red[2] + red[3] + b2[0];
    __syncthreads();
  }
}

// ---------------- compaction: selected -> comp, complement -> ucomp ----------
__global__ __launch_bounds__(1024) void compact_kernel(
    const float* __restrict__ scores, const float* __restrict__ thr,
    int* __restrict__ comp, int* __restrict__ ucomp) {
  __shared__ int wc_eq[16], wc_sel[16], red[16];
  const int b = blockIdx.x;
  const float T = thr[b];
  const float* srow = scores + (size_t)b * S_;
  const int tid = threadIdx.x, lane = tid & 63, wid = tid >> 6;

  // exact count of strictly-greater
  int cgt = 0;
  #pragma unroll
  for (int c = 0; c < 8; ++c) cgt += (srow[c * 1024 + tid] > T) ? 1 : 0;
  cgt += __shfl_xor(cgt, 1);  cgt += __shfl_xor(cgt, 2);  cgt += __shfl_xor(cgt, 4);
  cgt += __shfl_xor(cgt, 8);  cgt += __shfl_xor(cgt, 16); cgt += __shfl_xor(cgt, 32);
  if (lane == 0) red[wid] = cgt;
  __syncthreads();
  int cnt_gt = 0;
  #pragma unroll
  for (int i = 0; i < 16; ++i) cnt_gt += red[i];
  const int need = CAP_ - cnt_gt;

  int* crow = comp + b * CAP_;
  int* urow = ucomp + b * UCAP_;
  int sel_base = 0, unsel_base = 0, eq_base = 0;
  __syncthreads();
  for (int c = 0; c < 8; ++c) {
    int idx = c * 1024 + tid;
    float s = srow[idx];
    bool gt = s > T, eq = (s == T);
    unsigned long long meq = __ballot(eq);
    if (lane == 0) wc_eq[wid] = __popcll(meq);
    __syncthreads();
    int eq_off = eq_base, eq_tot = 0;
    #pragma unroll
    for (int w2 = 0; w2 < 16; ++w2) { if (w2 < wid) eq_off += wc_eq[w2]; eq_tot += wc_eq[w2]; }
    int eqpos = eq_off + __popcll(meq & ((1ull << lane) - 1));
    bool take = gt || (eq && eqpos < need);
    unsigned long long mt = __ballot(take);
    if (lane == 0) wc_sel[wid] = __popcll(mt);
    __syncthreads();
    int sel_off = sel_base, sel_tot = 0;
    #pragma unroll
    for (int w2 = 0; w2 < 16; ++w2) { if (w2 < wid) sel_off += wc_sel[w2]; sel_tot += wc_sel[w2]; }
    if (take) {
      crow[sel_off + __popcll(mt & ((1ull << lane) - 1))] = idx;
    } else {
      int un_off = unsel_base + wid * 64 - (sel_off - sel_base);
      urow[un_off + __popcll(~mt & ((1ull << lane) - 1))] = idx;
    }
    sel_base += sel_tot; unsel_base += 1024 - sel_tot; eq_base += eq_tot;
    __syncthreads();
  }
}

// ---------------- routing weights ----------------
__global__ __launch_bounds__(256) void rw_kernel(
    const float* __restrict__ scores, float* __restrict__ rw) {
  int i = blockIdx.x * 256 + threadIdx.x;
  rw[i] = 1.f / (1.f + expf(-scores[i]));
}

// ---------------- copy unselected rows (dense over ucomp) ----------------
__global__ __launch_bounds__(256) void copy_unsel_kernel(
    const float* __restrict__ x, const int* __restrict__ ucomp,
    float* __restrict__ out) {
  int i = blockIdx.x;                    // 0..B_*UCAP_-1
  int b = i >> 12, r = i & (UCAP_ - 1);
  int token = ucomp[b * UCAP_ + r];
  size_t row = (size_t)b * S_ + token;
  const float4* src = (const float4*)(x + row * H_);
  float4* dst = (float4*)(out + row * H_);
  dst[threadIdx.x] = src[threadIdx.x];
}

// ---------------- Wl -> WlT (bf16, transposed) ----------------
__global__ __launch_bounds__(256) void wlt_kernel(
    const float* __restrict__ wl, unsigned short* __restrict__ wlt) {
  __shared__ float tile[32][33];
  const int x0 = blockIdx.x * 32, y0 = blockIdx.y * 32;
  const int tx = threadIdx.x, ty = threadIdx.y;
  for (int i = ty; i < 32; i += 8) tile[i][tx] = wl[(size_t)(y0 + i) * H_ + x0 + tx];
  __syncthreads();
  for (int i = ty; i < 32; i += 8)
    wlt[(size_t)(x0 + i) * H_ + y0 + tx] = f2bf(tile[tx][i]);
}

// ---------------- gather selected rows, cast bf16 ----------------
__global__ __launch_bounds__(256) void gather_cast_kernel(
    const float* __restrict__ x, const int* __restrict__ comp,
    unsigned short* __restrict__ xg) {
  int tid = blockIdx.x * 256 + threadIdx.x;
  int rowc = tid >> 8;
  int c4 = tid & 255;
  int b = rowc >> 12, cc = rowc & (CAP_ - 1);
  int token = comp[b * CAP_ + cc];
  float4 v = *(const float4*)&x[((size_t)(b * S_ + token)) * H_ + c4 * 4];
  ushort4 o;
  o.x = f2bf(v.x); o.y = f2bf(v.y); o.z = f2bf(v.z); o.w = f2bf(v.w);
  *(ushort4*)&xg[(size_t)rowc * H_ + c4 * 4] = o;
}

// ---------------- main GEMM: out[selected] = gelu(xg @ WlT^T) ----------------
// BK=64, swizzled LDS; grid n-fastest so consecutive blocks share the A-panel.
__global__ __launch_bounds__(256) void moe_gemm_kernel(
    const unsigned short* __restrict__ xg, const unsigned short* __restrict__ wlt,
    const int* __restrict__ comp, float* __restrict__ out) {
  __shared__ __align__(16) unsigned short As[128 * 64];
  __shared__ __align__(16) unsigned short Bs[128 * 64];
  __shared__ int toks[128];
  const int t = threadIdx.x;
  const int lane = t & 63, w = t >> 6;
  const int n0 = blockIdx.x * 128, m0 = blockIdx.y * 128;
  const int bb = m0 >> 12;
  if (t < 128) toks[t] = comp[bb * CAP_ + (m0 & (CAP_ - 1)) + t];
  const int wr = w >> 1, wc = w & 1;
  const int r16 = lane & 15, ks = lane >> 4;

  const unsigned short* aS[4];
  const unsigned short* bS[4];
  #pragma unroll
  for (int u = 0; u < 4; ++u) {
    int c = u * 256 + t;
    int row = c >> 3, sl = c & 7;
    int slz = sl ^ (row & 7);
    aS[u] = xg + (size_t)(m0 + row) * H_ + slz * 8;
    bS[u] = wlt + (size_t)(n0 + row) * H_ + slz * 8;
  }

  f32x4 acc[4][4];
  #pragma unroll
  for (int i = 0; i < 4; ++i)
    #pragma unroll
    for (int j = 0; j < 4; ++j) acc[i][j] = (f32x4){0.f, 0.f, 0.f, 0.f};

  for (int k0 = 0; k0 < H_; k0 += 64) {
    #pragma unroll
    for (int u = 0; u < 4; ++u) {
      gload_lds16(aS[u] + k0, &As[(u * 256 + w * 64) * 8]);
      gload_lds16(bS[u] + k0, &Bs[(u * 256 + w * 64) * 8]);
    }
    __syncthreads();
    #pragma unroll
    for (int kk = 0; kk < 2; ++kk) {
      s16x8 af[4], bfr[4];
      const int g = kk * 4 + ks;
      #pragma unroll
      for (int i = 0; i < 4; ++i) {
        int r = wr * 64 + i * 16 + r16;
        af[i] = *(const s16x8*)&As[r * 64 + (g ^ (r & 7)) * 8];
      }
      #pragma unroll
      for (int j = 0; j < 4; ++j) {
        int r = wc * 64 + j * 16 + r16;
        bfr[j] = *(const s16x8*)&Bs[r * 64 + (g ^ (r & 7)) * 8];
      }
      #pragma unroll
      for (int i = 0; i < 4; ++i)
        #pragma unroll
        for (int j = 0; j < 4; ++j)
          acc[i][j] = __builtin_amdgcn_mfma_f32_16x16x32_bf16(af[i], bfr[j], acc[i][j], 0, 0, 0);
    }
    __syncthreads();
  }

  #pragma unroll
  for (int i = 0; i < 4; ++i) {
    #pragma unroll
    for (int r = 0; r < 4; ++r) {
      int rl = wr * 64 + i * 16 + (lane >> 4) * 4 + r;
      int token = toks[rl];
      float* orow = out + ((size_t)(bb * S_ + token)) * H_ + n0 + wc * 64;
      #pragma unroll
      for (int j = 0; j < 4; ++j)
        orow[j * 16 + r16] = gelu_f(acc[i][j][r]);
    }
  }
}

extern "C" void kernel_launch(void* const* d_in, const int* in_sizes, int n_in,
                              void* d_out, int out_size, void* d_ws, size_t ws_size,
                              hipStream_t stream) {
  const float* x  = (const float*)d_in[0];
  const float* W1 = (const float*)d_in[1];
  const float* b1 = (const float*)d_in[2];
  const float* W2 = (const float*)d_in[3];
  const float* b2 = (const float*)d_in[4];
  const float* Wl = (const float*)d_in[5];
  float* out = (float*)d_out;
  float* rw  = out + (size_t)B_ * S_ * H_;

  char* ws = (char*)d_ws;
  float* scores        = (float*)ws;                                 // 256 KB
  int*   comp          = (int*)(ws + (256 << 10));                   // 128 KB
  float* thr           = (float*)(ws + (384 << 10));                 // 32 B
  int*   count         = (int*)(ws + (384 << 10) + 256);             // 4 B
  int*   list          = (int*)(ws + (384 << 10) + 512);             // 32 KB
  int*   ucomp         = (int*)(ws + (448 << 10));                   // 128 KB
  unsigned short* wlt  = (unsigned short*)(ws + (1 << 20));          // 2 MB
  unsigned short* xg   = (unsigned short*)(ws + (3 << 20));          // 64 MB
  unsigned short* w1t_hi = xg;               // 512 KB (dead before xg written)
  unsigned short* w1t_lo = xg + 262144;      // 512 KB

  hipMemsetAsync(count, 0, sizeof(int), stream);
  hipLaunchKernelGGL(prep_w1_kernel, dim3(HQ_/32, H_/32), dim3(32, 8), 0, stream,
                     W1, w1t_hi, w1t_lo);
  hipLaunchKernelGGL(router_mfma_kernel, dim3((B_*S_)/128), dim3(512), 0, stream,
                     x, w1t_hi, w1t_lo, b1, W2, b2, scores);
  hipLaunchKernelGGL(select_kernel, dim3(B_), dim3(1024), 0, stream, scores, thr);
  hipLaunchKernelGGL(band_kernel, dim3((B_*S_)/256), dim3(256), 0, stream,
                     scores, thr, list, count);
  hipLaunchKernelGGL(recompute_kernel, dim3(256), dim3(256), 0, stream,
                     x, W1, b1, W2, b2, list, count, scores);
  hipLaunchKernelGGL(select_kernel, dim3(B_), dim3(1024), 0, stream, scores, thr);
  hipLaunchKernelGGL(compact_kernel, dim3(B_), dim3(1024), 0, stream,
                     scores, thr, comp, ucomp);
  hipLaunchKernelGGL(rw_kernel, dim3((B_*S_)/256), dim3(256), 0, stream,
                     scores, rw);
  hipLaunchKernelGGL(copy_unsel_kernel, dim3(B_*UCAP_), dim3(256), 0, stream,
                     x, ucomp, out);
  hipLaunchKernelGGL(wlt_kernel, dim3(H_/32, H_/32), dim3(32, 8), 0, stream, Wl, wlt);
  hipLaunchKernelGGL(gather_cast_kernel, dim3(M_*H_/4/256), dim3(256), 0, stream,
                     x, comp, xg);
  hipLaunchKernelGGL(moe_gemm_kernel, dim3(H_/128, M_/128), dim3(256), 0, stream,
                     xg, wlt, comp, out);
}

// Round 5
// 417.153 us; speedup vs baseline: 1.6972x; 1.0207x over previous
//
#include <hip/hip_runtime.h>
#include <stdint.h>

#define B_   8
#define S_   8192
#define H_   1024
#define HQ_  256
#define CAP_ 4096
#define UCAP_ (S_-CAP_)
#define M_   (B_*CAP_)   // 32768
#define EPSB 5e-3f
#define LCAP 8192

using f32x4 = __attribute__((ext_vector_type(4))) float;
using s16x8 = __attribute__((ext_vector_type(8))) short;

__device__ __forceinline__ unsigned short f2bf(float f) {
  unsigned u = __float_as_uint(f);
  u += 0x7FFF + ((u >> 16) & 1);   // RNE
  return (unsigned short)(u >> 16);
}
__device__ __forceinline__ float bf2f(unsigned short h) {
  return __uint_as_float(((unsigned)h) << 16);
}

// gelu tanh-approx via hw exp: 0.5v(1+tanh(z)) == v * sigmoid(2z)
__device__ __forceinline__ float gelu_f(float v) {
  float s = v + 0.044715f * v * v * v;
  float e = __expf(-1.5957691216057308f * s);
  return v * __builtin_amdgcn_rcpf(1.0f + e);
}

// monotonic fp32 <-> u32 key
__device__ __forceinline__ unsigned mono(float f) {
  unsigned u = __float_as_uint(f);
  return (u & 0x80000000u) ? ~u : (u | 0x80000000u);
}
__device__ __forceinline__ float unmono(unsigned k) {
  unsigned u = (k & 0x80000000u) ? (k & 0x7fffffffu) : ~k;
  return __uint_as_float(u);
}

__device__ __forceinline__ void gload_lds16(const void* g, void* l) {
  __builtin_amdgcn_global_load_lds(
      (const __attribute__((address_space(1))) void*)(uintptr_t)g,
      (__attribute__((address_space(3))) void*)(uintptr_t)l,
      16, 0, 0);
}

// ---------------- W1 -> transposed bf16 hi/lo split ----------------
__global__ __launch_bounds__(256) void prep_w1_kernel(
    const float* __restrict__ W1, unsigned short* __restrict__ w1t_hi,
    unsigned short* __restrict__ w1t_lo) {
  __shared__ float tile[32][33];
  const int n0 = blockIdx.x * 32, k0 = blockIdx.y * 32;
  const int tx = threadIdx.x, ty = threadIdx.y;
  for (int i = ty; i < 32; i += 8) tile[i][tx] = W1[(size_t)(k0 + i) * HQ_ + n0 + tx];
  __syncthreads();
  for (int i = ty; i < 32; i += 8) {
    float v = tile[tx][i];
    unsigned short h = f2bf(v);
    w1t_hi[(size_t)(n0 + i) * H_ + k0 + tx] = h;
    w1t_lo[(size_t)(n0 + i) * H_ + k0 + tx] = f2bf(v - bf2f(h));
  }
}

// ---------------- Router GEMM: x_hi @ (W_hi + W_lo), fused relu/W2 ----------
// error sigma ~0.8e-3 (x_lo term dropped) -> exact band recompute at 5e-3
__global__ __launch_bounds__(512) void router_mfma_kernel(
    const float* __restrict__ x, const unsigned short* __restrict__ w1t_hi,
    const unsigned short* __restrict__ w1t_lo, const float* __restrict__ b1,
    const float* __restrict__ W2, const float* __restrict__ b2,
    float* __restrict__ scores) {
  __shared__ __align__(16) unsigned short AsH[128 * 32];
  __shared__ __align__(16) unsigned short BsH[256 * 32];
  __shared__ __align__(16) unsigned short BsL[256 * 32];
  __shared__ float part[128][4];
  const int t = threadIdx.x;
  const int lane = t & 63, w = t >> 6;
  const int m0 = blockIdx.x * 128;
  const int wr = w >> 2, wc = w & 3;
  const int r16 = lane & 15, ks = lane >> 4;

  f32x4 acc[4][4];
  #pragma unroll
  for (int i = 0; i < 4; ++i)
    #pragma unroll
    for (int j = 0; j < 4; ++j) acc[i][j] = (f32x4){0.f, 0.f, 0.f, 0.f};

  for (int k0 = 0; k0 < H_; k0 += 32) {
    // A: reg-stage fp32 -> hi bf16, swizzled 16B-chunk write
    #pragma unroll
    for (int u = 0; u < 2; ++u) {
      int idx = t + u * 512;
      int row = idx >> 3, q = idx & 7;
      float4 v = *(const float4*)&x[(size_t)(m0 + row) * H_ + k0 + q * 4];
      ushort4 hh;
      hh.x = f2bf(v.x); hh.y = f2bf(v.y); hh.z = f2bf(v.z); hh.w = f2bf(v.w);
      int so = row * 32 + (((q >> 1) ^ (row & 3)) << 3) + (q & 1) * 4;
      *(ushort4*)&AsH[so] = hh;
    }
    // B: gload_lds with pre-swizzled per-lane global source (rule 21)
    #pragma unroll
    for (int q = 0; q < 2; ++q) {
      int c0 = (q * 8 + w) * 64;
      int g = c0 + lane;
      int row = g >> 2, sl = g & 3;
      int slz = sl ^ (row & 3);
      gload_lds16(&w1t_hi[(size_t)row * H_ + k0 + slz * 8], &BsH[c0 * 8]);
      gload_lds16(&w1t_lo[(size_t)row * H_ + k0 + slz * 8], &BsL[c0 * 8]);
    }
    __syncthreads();
    s16x8 ah[4], bh[4], bl[4];
    #pragma unroll
    for (int i = 0; i < 4; ++i) {
      int r = wr * 64 + i * 16 + r16;
      int co = (ks ^ (r & 3)) * 8;
      ah[i] = *(const s16x8*)&AsH[r * 32 + co];
    }
    #pragma unroll
    for (int j = 0; j < 4; ++j) {
      int r = wc * 64 + j * 16 + r16;
      int co = (ks ^ (r & 3)) * 8;
      bh[j] = *(const s16x8*)&BsH[r * 32 + co];
      bl[j] = *(const s16x8*)&BsL[r * 32 + co];
    }
    #pragma unroll
    for (int i = 0; i < 4; ++i)
      #pragma unroll
      for (int j = 0; j < 4; ++j) {
        acc[i][j] = __builtin_amdgcn_mfma_f32_16x16x32_bf16(ah[i], bh[j], acc[i][j], 0, 0, 0);
        acc[i][j] = __builtin_amdgcn_mfma_f32_16x16x32_bf16(ah[i], bl[j], acc[i][j], 0, 0, 0);
      }
    __syncthreads();
  }

  float b1v[4], w2v[4];
  #pragma unroll
  for (int j = 0; j < 4; ++j) {
    int n = wc * 64 + j * 16 + r16;
    b1v[j] = b1[n]; w2v[j] = W2[n];
  }
  const int g4 = lane >> 4;
  #pragma unroll
  for (int i = 0; i < 4; ++i) {
    #pragma unroll
    for (int r = 0; r < 4; ++r) {
      float p = 0.f;
      #pragma unroll
      for (int j = 0; j < 4; ++j) {
        float h = acc[i][j][r] + b1v[j];
        h = fmaxf(h, 0.f);
        p = fmaf(h, w2v[j], p);
      }
      p += __shfl_xor(p, 1);
      p += __shfl_xor(p, 2);
      p += __shfl_xor(p, 4);
      p += __shfl_xor(p, 8);
      if (r16 == 0) part[wr * 64 + i * 16 + g4 * 4 + r][wc] = p;
    }
  }
  __syncthreads();
  if (t < 128)
    scores[m0 + t] = part[t][0] + part[t][1] + part[t][2] + part[t][3] + b2[0];
}

// ---------------- exact radix-select: T = CAP_-th largest per row ------------
__global__ __launch_bounds__(1024) void select_kernel(
    const float* __restrict__ scores, float* __restrict__ thr) {
  __shared__ unsigned hist[2048];
  __shared__ unsigned sh_b, sh_gt;
  const int b = blockIdx.x;
  const int tid = threadIdx.x;
  const float* srow = scores + (size_t)b * S_;
  unsigned prefix = 0; int plen = 0; unsigned rank = CAP_;
  #pragma unroll
  for (int round = 0; round < 3; ++round) {
    const int nb = (round < 2) ? 11 : 10;
    hist[tid] = 0; hist[tid + 1024] = 0;
    __syncthreads();
    for (int i = tid; i < S_; i += 1024) {
      unsigned k = mono(srow[i]);
      if (plen == 0 || (k >> (32 - plen)) == prefix) {
        unsigned bucket = (k << plen) >> (32 - nb);
        atomicAdd(&hist[bucket], 1u);
      }
    }
    __syncthreads();
    for (int s = 1; s < 2048; s <<= 1) {
      unsigned t0 = (tid + s < 2048) ? hist[tid + s] : 0;
      unsigned t1 = (tid + 1024 + s < 2048) ? hist[tid + 1024 + s] : 0;
      __syncthreads();
      hist[tid] += t0; hist[tid + 1024] += t1;
      __syncthreads();
    }
    #pragma unroll
    for (int h = 0; h < 2; ++h) {
      int i = tid + h * 1024;
      unsigned ge = hist[i];
      unsigned gt = (i < 2047) ? hist[i + 1] : 0;
      if (gt < rank && rank <= ge) { sh_b = (unsigned)i; sh_gt = gt; }
    }
    __syncthreads();
    prefix = (prefix << nb) | sh_b;
    plen += nb;
    rank -= sh_gt;
    __syncthreads();
  }
  if (tid == 0) thr[b] = unmono(prefix);
}

// ---------------- band flag: tokens near threshold ----------------
__global__ __launch_bounds__(256) void band_kernel(
    const float* __restrict__ scores, const float* __restrict__ thr,
    int* __restrict__ list, int* __restrict__ count) {
  int i = blockIdx.x * 256 + threadIdx.x;
  float s = scores[i];
  int b = i >> 13;
  if (fabsf(s - thr[b]) <= EPSB) {
    int p = atomicAdd(count, 1);
    if (p < LCAP) list[p] = i;
  }
}

// ---------------- exact fp32 recompute, 4 tokens/block share W1 pass ---------
__global__ __launch_bounds__(256) void recompute_kernel(
    const float* __restrict__ x, const float* __restrict__ W1,
    const float* __restrict__ b1, const float* __restrict__ W2,
    const float* __restrict__ b2, const int* __restrict__ list,
    const int* __restrict__ count, float* __restrict__ scores) {
  __shared__ float xr[4][H_];
  __shared__ float red[4][4];
  int n = *count; if (n > LCAP) n = LCAP;
  const int j = threadIdx.x;
  for (int base = blockIdx.x * 4; base < n; base += gridDim.x * 4) {
    int nt = n - base; if (nt > 4) nt = 4;
    for (int tt = 0; tt < 4; ++tt) {
      int tok = list[base + ((tt < nt) ? tt : 0)];
      const float* xrow = x + (size_t)tok * H_;
      for (int k = j; k < H_; k += 256) xr[tt][k] = xrow[k];
    }
    __syncthreads();
    float a0 = 0.f, a1 = 0.f, a2 = 0.f, a3 = 0.f;
    for (int k = 0; k < H_; ++k) {
      float wv = W1[(size_t)k * HQ_ + j];
      a0 = fmaf(xr[0][k], wv, a0);
      a1 = fmaf(xr[1][k], wv, a1);
      a2 = fmaf(xr[2][k], wv, a2);
      a3 = fmaf(xr[3][k], wv, a3);
    }
    float aa[4] = {a0, a1, a2, a3};
    #pragma unroll
    for (int tt = 0; tt < 4; ++tt) {
      float h = fmaxf(aa[tt] + b1[j], 0.f);
      float v = h * W2[j];
      v += __shfl_xor(v, 1);  v += __shfl_xor(v, 2);  v += __shfl_xor(v, 4);
      v += __shfl_xor(v, 8);  v += __shfl_xor(v, 16); v += __shfl_xor(v, 32);
      if ((j & 63) == 0) red[tt][j >> 6] = v;
    }
    __syncthreads();
    if (j < nt)
      scores[list[base + j]] = red[j][0] + red[j][1] + red[j][2] + red[j][3] + b2[0];
    __syncthreads();
  }
}

// ---------------- compaction: selected -> comp, complement -> ucomp ----------
__global__ __launch_bounds__(1024) void compact_kernel(
    const float* __restrict__ scores, const float* __restrict__ thr,
    int* __restrict__ comp, int* __restrict__ ucomp) {
  __shared__ int wc_eq[16], wc_sel[16], red[16];
  const int b = blockIdx.x;
  const float T = thr[b];
  const float* srow = scores + (size_t)b * S_;
  const int tid = threadIdx.x, lane = tid & 63, wid = tid >> 6;

  int cgt = 0;
  #pragma unroll
  for (int c = 0; c < 8; ++c) cgt += (srow[c * 1024 + tid] > T) ? 1 : 0;
  cgt += __shfl_xor(cgt, 1);  cgt += __shfl_xor(cgt, 2);  cgt += __shfl_xor(cgt, 4);
  cgt += __shfl_xor(cgt, 8);  cgt += __shfl_xor(cgt, 16); cgt += __shfl_xor(cgt, 32);
  if (lane == 0) red[wid] = cgt;
  __syncthreads();
  int cnt_gt = 0;
  #pragma unroll
  for (int i = 0; i < 16; ++i) cnt_gt += red[i];
  const int need = CAP_ - cnt_gt;

  int* crow = comp + b * CAP_;
  int* urow = ucomp + b * UCAP_;
  int sel_base = 0, unsel_base = 0, eq_base = 0;
  __syncthreads();
  for (int c = 0; c < 8; ++c) {
    int idx = c * 1024 + tid;
    float s = srow[idx];
    bool gt = s > T, eq = (s == T);
    unsigned long long meq = __ballot(eq);
    if (lane == 0) wc_eq[wid] = __popcll(meq);
    __syncthreads();
    int eq_off = eq_base, eq_tot = 0;
    #pragma unroll
    for (int w2 = 0; w2 < 16; ++w2) { if (w2 < wid) eq_off += wc_eq[w2]; eq_tot += wc_eq[w2]; }
    int eqpos = eq_off + __popcll(meq & ((1ull << lane) - 1));
    bool take = gt || (eq && eqpos < need);
    unsigned long long mt = __ballot(take);
    if (lane == 0) wc_sel[wid] = __popcll(mt);
    __syncthreads();
    int sel_off = sel_base, sel_tot = 0;
    #pragma unroll
    for (int w2 = 0; w2 < 16; ++w2) { if (w2 < wid) sel_off += wc_sel[w2]; sel_tot += wc_sel[w2]; }
    if (take) {
      crow[sel_off + __popcll(mt & ((1ull << lane) - 1))] = idx;
    } else {
      int un_off = unsel_base + wid * 64 - (sel_off - sel_base);
      urow[un_off + __popcll(~mt & ((1ull << lane) - 1))] = idx;
    }
    sel_base += sel_tot; unsel_base += 1024 - sel_tot; eq_base += eq_tot;
    __syncthreads();
  }
}

// ---------------- routing weights ----------------
__global__ __launch_bounds__(256) void rw_kernel(
    const float* __restrict__ scores, float* __restrict__ rw) {
  int i = blockIdx.x * 256 + threadIdx.x;
  rw[i] = 1.f / (1.f + expf(-scores[i]));
}

// ---------------- copy unselected rows (dense over ucomp) ----------------
__global__ __launch_bounds__(256) void copy_unsel_kernel(
    const float* __restrict__ x, const int* __restrict__ ucomp,
    float* __restrict__ out) {
  int i = blockIdx.x;
  int b = i >> 12, r = i & (UCAP_ - 1);
  int token = ucomp[b * UCAP_ + r];
  size_t row = (size_t)b * S_ + token;
  const float4* src = (const float4*)(x + row * H_);
  float4* dst = (float4*)(out + row * H_);
  dst[threadIdx.x] = src[threadIdx.x];
}

// ---------------- Wl -> WlT (bf16, transposed) ----------------
__global__ __launch_bounds__(256) void wlt_kernel(
    const float* __restrict__ wl, unsigned short* __restrict__ wlt) {
  __shared__ float tile[32][33];
  const int x0 = blockIdx.x * 32, y0 = blockIdx.y * 32;
  const int tx = threadIdx.x, ty = threadIdx.y;
  for (int i = ty; i < 32; i += 8) tile[i][tx] = wl[(size_t)(y0 + i) * H_ + x0 + tx];
  __syncthreads();
  for (int i = ty; i < 32; i += 8)
    wlt[(size_t)(x0 + i) * H_ + y0 + tx] = f2bf(tile[tx][i]);
}

// ---------------- gather selected rows, cast bf16 ----------------
__global__ __launch_bounds__(256) void gather_cast_kernel(
    const float* __restrict__ x, const int* __restrict__ comp,
    unsigned short* __restrict__ xg) {
  int tid = blockIdx.x * 256 + threadIdx.x;
  int rowc = tid >> 8;
  int c4 = tid & 255;
  int b = rowc >> 12, cc = rowc & (CAP_ - 1);
  int token = comp[b * CAP_ + cc];
  float4 v = *(const float4*)&x[((size_t)(b * S_ + token)) * H_ + c4 * 4];
  ushort4 o;
  o.x = f2bf(v.x); o.y = f2bf(v.y); o.z = f2bf(v.z); o.w = f2bf(v.w);
  *(ushort4*)&xg[(size_t)rowc * H_ + c4 * 4] = o;
}

// ---------------- main GEMM: out[selected] = gelu(xg @ WlT^T) ----------------
// BK=64, swizzled LDS; XCD-aware mapping: xcd = bid&7 owns 32 contiguous
// m-panels, n-fastest inside -> A-panel + full B fit one XCD's L2.
__global__ __launch_bounds__(256) void moe_gemm_kernel(
    const unsigned short* __restrict__ xg, const unsigned short* __restrict__ wlt,
    const int* __restrict__ comp, float* __restrict__ out) {
  __shared__ __align__(16) unsigned short As[128 * 64];
  __shared__ __align__(16) unsigned short Bs[128 * 64];
  __shared__ int toks[128];
  const int t = threadIdx.x;
  const int lane = t & 63, w = t >> 6;
  const int bid = blockIdx.x;
  const int xcd = bid & 7, wl_ = bid >> 3;
  const int m0 = (xcd * 32 + (wl_ >> 3)) * 128;
  const int n0 = (wl_ & 7) * 128;
  const int bb = m0 >> 12;
  if (t < 128) toks[t] = comp[bb * CAP_ + (m0 & (CAP_ - 1)) + t];
  const int wr = w >> 1, wc = w & 1;
  const int r16 = lane & 15, ks = lane >> 4;

  const unsigned short* aS[4];
  const unsigned short* bS[4];
  #pragma unroll
  for (int u = 0; u < 4; ++u) {
    int c = u * 256 + t;
    int row = c >> 3, sl = c & 7;
    int slz = sl ^ (row & 7);
    aS[u] = xg + (size_t)(m0 + row) * H_ + slz * 8;
    bS[u] = wlt + (size_t)(n0 + row) * H_ + slz * 8;
  }

  f32x4 acc[4][4];
  #pragma unroll
  for (int i = 0; i < 4; ++i)
    #pragma unroll
    for (int j = 0; j < 4; ++j) acc[i][j] = (f32x4){0.f, 0.f, 0.f, 0.f};

  for (int k0 = 0; k0 < H_; k0 += 64) {
    #pragma unroll
    for (int u = 0; u < 4; ++u) {
      gload_lds16(aS[u] + k0, &As[(u * 256 + w * 64) * 8]);
      gload_lds16(bS[u] + k0, &Bs[(u * 256 + w * 64) * 8]);
    }
    __syncthreads();
    #pragma unroll
    for (int kk = 0; kk < 2; ++kk) {
      s16x8 af[4], bfr[4];
      const int g = kk * 4 + ks;
      #pragma unroll
      for (int i = 0; i < 4; ++i) {
        int r = wr * 64 + i * 16 + r16;
        af[i] = *(const s16x8*)&As[r * 64 + (g ^ (r & 7)) * 8];
      }
      #pragma unroll
      for (int j = 0; j < 4; ++j) {
        int r = wc * 64 + j * 16 + r16;
        bfr[j] = *(const s16x8*)&Bs[r * 64 + (g ^ (r & 7)) * 8];
      }
      #pragma unroll
      for (int i = 0; i < 4; ++i)
        #pragma unroll
        for (int j = 0; j < 4; ++j)
          acc[i][j] = __builtin_amdgcn_mfma_f32_16x16x32_bf16(af[i], bfr[j], acc[i][j], 0, 0, 0);
    }
    __syncthreads();
  }

  #pragma unroll
  for (int i = 0; i < 4; ++i) {
    #pragma unroll
    for (int r = 0; r < 4; ++r) {
      int rl = wr * 64 + i * 16 + (lane >> 4) * 4 + r;
      int token = toks[rl];
      float* orow = out + ((size_t)(bb * S_ + token)) * H_ + n0 + wc * 64;
      #pragma unroll
      for (int j = 0; j < 4; ++j)
        orow[j * 16 + r16] = gelu_f(acc[i][j][r]);
    }
  }
}

extern "C" void kernel_launch(void* const* d_in, const int* in_sizes, int n_in,
                              void* d_out, int out_size, void* d_ws, size_t ws_size,
                              hipStream_t stream) {
  const float* x  = (const float*)d_in[0];
  const float* W1 = (const float*)d_in[1];
  const float* b1 = (const float*)d_in[2];
  const float* W2 = (const float*)d_in[3];
  const float* b2 = (const float*)d_in[4];
  const float* Wl = (const float*)d_in[5];
  float* out = (float*)d_out;
  float* rw  = out + (size_t)B_ * S_ * H_;

  char* ws = (char*)d_ws;
  float* scores        = (float*)ws;                                 // 256 KB
  int*   comp          = (int*)(ws + (256 << 10));                   // 128 KB
  float* thr           = (float*)(ws + (384 << 10));                 // 32 B
  int*   count         = (int*)(ws + (384 << 10) + 256);             // 4 B
  int*   list          = (int*)(ws + (384 << 10) + 512);             // 32 KB
  int*   ucomp         = (int*)(ws + (448 << 10));                   // 128 KB
  unsigned short* wlt  = (unsigned short*)(ws + (1 << 20));          // 2 MB
  unsigned short* xg   = (unsigned short*)(ws + (3 << 20));          // 64 MB
  unsigned short* w1t_hi = xg;               // 512 KB (dead before xg written)
  unsigned short* w1t_lo = xg + 262144;      // 512 KB

  hipMemsetAsync(count, 0, sizeof(int), stream);
  hipLaunchKernelGGL(prep_w1_kernel, dim3(HQ_/32, H_/32), dim3(32, 8), 0, stream,
                     W1, w1t_hi, w1t_lo);
  hipLaunchKernelGGL(router_mfma_kernel, dim3((B_*S_)/128), dim3(512), 0, stream,
                     x, w1t_hi, w1t_lo, b1, W2, b2, scores);
  hipLaunchKernelGGL(select_kernel, dim3(B_), dim3(1024), 0, stream, scores, thr);
  hipLaunchKernelGGL(band_kernel, dim3((B_*S_)/256), dim3(256), 0, stream,
                     scores, thr, list, count);
  hipLaunchKernelGGL(recompute_kernel, dim3(128), dim3(256), 0, stream,
                     x, W1, b1, W2, b2, list, count, scores);
  hipLaunchKernelGGL(select_kernel, dim3(B_), dim3(1024), 0, stream, scores, thr);
  hipLaunchKernelGGL(compact_kernel, dim3(B_), dim3(1024), 0, stream,
                     scores, thr, comp, ucomp);
  hipLaunchKernelGGL(rw_kernel, dim3((B_*S_)/256), dim3(256), 0, stream,
                     scores, rw);
  hipLaunchKernelGGL(copy_unsel_kernel, dim3(B_*UCAP_), dim3(256), 0, stream,
                     x, ucomp, out);
  hipLaunchKernelGGL(wlt_kernel, dim3(H_/32, H_/32), dim3(32, 8), 0, stream, Wl, wlt);
  hipLaunchKernelGGL(gather_cast_kernel, dim3(M_*H_/4/256), dim3(256), 0, stream,
                     x, comp, xg);
  hipLaunchKernelGGL(moe_gemm_kernel, dim3((M_/128)*(H_/128)), dim3(256), 0, stream,
                     xg, wlt, comp, out);
}